// Round 3
// baseline (1490.569 us; speedup 1.0000x reference)
//
#include <hip/hip_runtime.h>
#include <hip/hip_bf16.h>
#include <cstdint>

typedef __attribute__((ext_vector_type(8))) short short8;
typedef __attribute__((ext_vector_type(4))) float floatx4;
typedef __hip_bfloat16 bf16;
typedef unsigned short u16;

static constexpr int cN0 = 120000, cN1 = 24000, cN2 = 6000;
static constexpr int cD = 256, cHC1 = 512;
static constexpr int CH1 = 4800;   // layer-1 target chunk (5 chunks, %64==0)
static constexpr int CH2 = 3000;   // layer-2 target chunk (2 chunks, M-guarded)

// ---------- W1t[n*256+k] = bf16(W1[k*512+n]) ----------
__global__ __launch_bounds__(256)
void gat_w1t(const float* __restrict__ W1, u16* __restrict__ dst) {
  int t = blockIdx.x * 256 + threadIdx.x;  // t = n*256+k
  if (t >= 512 * 256) return;
  int n = t >> 8, k = t & 255;
  bf16 v = bf16(W1[(size_t)k * 512 + n]);
  dst[t] = *(u16*)&v;
}

// ---------- W2te[c*4096 + h*512 + k] = bf16(W2[k*2048 + h*256 + c]) ----------
__global__ __launch_bounds__(256)
void gat_make_w2te(const float* __restrict__ W2, u16* __restrict__ out) {
  int t = blockIdx.x * 256 + threadIdx.x;
  if (t >= 256 * 4096) return;
  int c = t >> 12, rem = t & 4095, h = rem >> 9, k = rem & 511;
  bf16 v = bf16(W2[(size_t)k * 2048 + h * 256 + c]);
  out[t] = *(u16*)&v;
}

// ---------- watt[h*K+k] = sum_c W[k*ldw + h*Ch + c] * att[h*Ch+c]  (all f32) ----------
__global__ __launch_bounds__(256)
void gat_make_watt(const float* __restrict__ W, const float* __restrict__ atts,
                   const float* __restrict__ attd, float* __restrict__ ws,
                   float* __restrict__ wd, int K, int Ch, int ldw) {
  int k = blockIdx.x * 256 + threadIdx.x;
  if (k >= K) return;
  for (int h = 0; h < 8; h++) {
    const float* Wr = W + (size_t)k * ldw + h * Ch;
    const float* as = atts + h * Ch;
    const float* ad = attd + h * Ch;
    float ss = 0.f, dd = 0.f;
    for (int c = 0; c < Ch; c++) {
      float wv = Wr[c];
      ss += wv * as[c];
      dd += wv * ad[c];
    }
    ws[h * K + k] = ss;
    wd[h * K + k] = dd;
  }
}

// ---------- a_s[n,h] = x[n,:] . watt_s[h,:]  (one wave per row) ----------
template<int K>
__global__ __launch_bounds__(256)
void gat_scores(const float* __restrict__ x, const float* __restrict__ wsrc,
                const float* __restrict__ wdst, float* __restrict__ a_s,
                float* __restrict__ a_d, int M, int MD) {
  constexpr int NK = K / 64;   // floats per lane: 4 or 8
  int lane = threadIdx.x & 63;
  int row = blockIdx.x * 4 + (threadIdx.x >> 6);
  if (row >= M) return;
  const float* xr = x + (size_t)row * K + lane * NK;
  float xv[NK];
#pragma unroll
  for (int j = 0; j < NK / 4; j++) {
    float4 v = ((const float4*)xr)[j];
    xv[4 * j] = v.x; xv[4 * j + 1] = v.y; xv[4 * j + 2] = v.z; xv[4 * j + 3] = v.w;
  }
  bool dodst = row < MD;
#pragma unroll
  for (int h = 0; h < 8; h++) {
    const float* wr  = wsrc + h * K + lane * NK;
    const float* wr2 = wdst + h * K + lane * NK;
    float v = 0.f, v2 = 0.f;
#pragma unroll
    for (int j = 0; j < NK / 4; j++) {
      float4 a = ((const float4*)wr)[j];
      float4 b = ((const float4*)wr2)[j];
      v  += xv[4*j]*a.x + xv[4*j+1]*a.y + xv[4*j+2]*a.z + xv[4*j+3]*a.w;
      v2 += xv[4*j]*b.x + xv[4*j+1]*b.y + xv[4*j+2]*b.z + xv[4*j+3]*b.w;
    }
#pragma unroll
    for (int o = 32; o; o >>= 1) { v += __shfl_down(v, o); v2 += __shfl_down(v2, o); }
    if (lane == 0) {
      a_s[row * 8 + h] = v;
      if (dodst) a_d[row * 8 + h] = v2;
    }
  }
}

// ---------- CSR build ----------
__global__ __launch_bounds__(256)
void gat_hist(const int* __restrict__ dstv, int* __restrict__ cnt, int E) {
  int t = blockIdx.x * 256 + threadIdx.x;
  if (t < E) atomicAdd(&cnt[dstv[t]], 1);
}

__global__ __launch_bounds__(1024)
void gat_scan_excl(const int* __restrict__ cnt, int* __restrict__ off, int n) {
  __shared__ int wsum[16];
  __shared__ int carry_s;
  int t = threadIdx.x, lane = t & 63, wid = t >> 6;
  if (t == 0) carry_s = 0;
  __syncthreads();
  for (int base = 0; base < n; base += 1024) {
    int idx = base + t;
    int v = (idx < n) ? cnt[idx] : 0;
    int x = v;
#pragma unroll
    for (int d = 1; d < 64; d <<= 1) { int y = __shfl_up(x, d); if (lane >= d) x += y; }
    if (lane == 63) wsum[wid] = x;
    __syncthreads();
    if (t < 16) {
      int s = wsum[t];
#pragma unroll
      for (int d = 1; d < 16; d <<= 1) { int y = __shfl_up(s, d); if (t >= d) s += y; }
      wsum[t] = s;
    }
    __syncthreads();
    int prefix = carry_s + (wid ? wsum[wid - 1] : 0) + x - v;
    if (idx < n) off[idx] = prefix;
    int tot = wsum[15];
    __syncthreads();
    if (t == 0) carry_s += tot;
    __syncthreads();
  }
  if (threadIdx.x == 0) off[n] = carry_s;
}

__global__ __launch_bounds__(256)
void gat_scatter(const int* __restrict__ dstv, const int* __restrict__ off,
                 int* __restrict__ cur, int* __restrict__ ids, int E) {
  int t = blockIdx.x * 256 + threadIdx.x;
  if (t < E) {
    int d = dstv[t];
    int p = atomicAdd(&cur[d], 1);
    ids[off[d] + p] = t;
  }
}

// ---------- ex = exp(leaky(a_src+a_dst)), denom += ex ----------
__global__ __launch_bounds__(256)
void gat_edge_pass(const int* __restrict__ src, const int* __restrict__ dstv,
                   const float* __restrict__ a_s, const float* __restrict__ a_d,
                   float* __restrict__ ex, float* __restrict__ denom, int E) {
  int t = blockIdx.x * 256 + threadIdx.x;
  if (t >= E) return;
  int s = src[t], d = dstv[t];
  const float* as = a_s + (size_t)s * 8;
  const float* ad = a_d + (size_t)d * 8;
  float4 s0 = *(const float4*)as, s1 = *(const float4*)(as + 4);
  float4 d0 = *(const float4*)ad, d1 = *(const float4*)(ad + 4);
  float ev[8] = { s0.x + d0.x, s0.y + d0.y, s0.z + d0.z, s0.w + d0.w,
                  s1.x + d1.x, s1.y + d1.y, s1.z + d1.z, s1.w + d1.w };
  float exv[8];
#pragma unroll
  for (int h = 0; h < 8; h++) {
    float e = ev[h];
    e = e > 0.f ? e : 0.2f * e;
    float xv = expf(e);   // shift-invariant softmax; |e| <~ 8 so no overflow
    exv[h] = xv;
    atomicAdd(&denom[(size_t)d * 8 + h], xv);
  }
  float4* op = (float4*)(ex + (size_t)t * 8);
  op[0] = make_float4(exv[0], exv[1], exv[2], exv[3]);
  op[1] = make_float4(exv[4], exv[5], exv[6], exv[7]);
}

// ---------- layer-1 input-space gather: agg[d,h,k] = sum alpha_h x[s,k] -> bf16 ----------
__global__ __launch_bounds__(256)
void gat_gather_in1(const float* __restrict__ x, const float* __restrict__ ex,
                    const float* __restrict__ den, const int* __restrict__ off,
                    const int* __restrict__ ids, const int* __restrict__ srcv,
                    u16* __restrict__ agg, int d0) {
  int d = d0 + blockIdx.x, t = threadIdx.x;  // t = k (0..255)
  int beg = off[d], end = off[d + 1];
  float inv[8];
#pragma unroll
  for (int j = 0; j < 8; j++) inv[j] = 1.f / den[(size_t)d * 8 + j];
  float acc[8] = {};
  int e_n = 0, s_n = 0;
  if (beg < end) { e_n = ids[beg]; s_n = srcv[e_n]; }
  for (int i = beg; i < end; i++) {
    int e = e_n, s = s_n;
    if (i + 1 < end) { e_n = ids[i + 1]; s_n = srcv[e_n]; }
    float4 e0 = *(const float4*)&ex[(size_t)e * 8];
    float4 e1 = *(const float4*)&ex[(size_t)e * 8 + 4];
    float xv = x[(size_t)s * cD + t];
    acc[0] += e0.x * inv[0] * xv; acc[1] += e0.y * inv[1] * xv;
    acc[2] += e0.z * inv[2] * xv; acc[3] += e0.w * inv[3] * xv;
    acc[4] += e1.x * inv[4] * xv; acc[5] += e1.y * inv[5] * xv;
    acc[6] += e1.z * inv[6] * xv; acc[7] += e1.w * inv[7] * xv;
  }
  u16* ap = agg + (size_t)blockIdx.x * 2048 + t;
#pragma unroll
  for (int j = 0; j < 8; j++) {
    bf16 v = bf16(acc[j]);
    ap[(size_t)j * 256] = *(u16*)&v;
  }
}

// ---------- layer-2 input-space gather: agg[d,h,k] (k<512) -> bf16 ----------
__global__ __launch_bounds__(256)
void gat_gather_in2(const float* __restrict__ x1, const float* __restrict__ ex,
                    const float* __restrict__ den, const int* __restrict__ off,
                    const int* __restrict__ ids, const int* __restrict__ srcv,
                    u16* __restrict__ agg, int d0) {
  int d = d0 + blockIdx.x, t = threadIdx.x;  // k pair: t, t+256
  int beg = off[d], end = off[d + 1];
  float inv[8];
#pragma unroll
  for (int j = 0; j < 8; j++) inv[j] = 1.f / den[(size_t)d * 8 + j];
  float acc0[8] = {}, acc1[8] = {};
  int e_n = 0, s_n = 0;
  if (beg < end) { e_n = ids[beg]; s_n = srcv[e_n]; }
  for (int i = beg; i < end; i++) {
    int e = e_n, s = s_n;
    if (i + 1 < end) { e_n = ids[i + 1]; s_n = srcv[e_n]; }
    float4 e0 = *(const float4*)&ex[(size_t)e * 8];
    float4 e1 = *(const float4*)&ex[(size_t)e * 8 + 4];
    float al[8] = { e0.x * inv[0], e0.y * inv[1], e0.z * inv[2], e0.w * inv[3],
                    e1.x * inv[4], e1.y * inv[5], e1.z * inv[6], e1.w * inv[7] };
    float xv0 = x1[(size_t)s * cHC1 + t];
    float xv1 = x1[(size_t)s * cHC1 + t + 256];
#pragma unroll
    for (int j = 0; j < 8; j++) { acc0[j] += al[j] * xv0; acc1[j] += al[j] * xv1; }
  }
  u16* ap = agg + (size_t)blockIdx.x * 4096;
#pragma unroll
  for (int j = 0; j < 8; j++) {
    bf16 v0 = bf16(acc0[j]), v1 = bf16(acc1[j]);
    ap[(size_t)j * 512 + t]       = *(u16*)&v0;
    ap[(size_t)j * 512 + t + 256] = *(u16*)&v1;
  }
}

// ---------- GEMM: C = A[M,K] @ Bt[N,K]^T (bf16 in, f32 out), M-guarded, fused epilogue ----------
// EPI=1: elu(v+bias) (layer-1 x1); EPI=2: v*0.125+bias (layer-2 out)
// grid: (ceil(M/64), N/BN, Z); per-z element offsets zA (A cols), zB (Bt elems), zC (C cols)
template<int BN, int EPI>
__global__ __launch_bounds__(256)
void gat_gemm(const u16* __restrict__ A, long lda, const u16* __restrict__ Bt, long ldb,
              float* __restrict__ C, long ldc, int M, int K,
              const float* __restrict__ bias, int zA, int zB, int zC, int zBias) {
  __shared__ __align__(16) u16 Al[64][72];   // +8 pad
  __shared__ __align__(16) u16 Bl[BN][72];
  const int tid = threadIdx.x;
  const int bm = blockIdx.x << 6;
  const int n0 = blockIdx.y * BN;
  const int z = blockIdx.z;
  const u16* Ab = A + (size_t)z * zA;
  const u16* Bb = Bt + (size_t)z * zB + (size_t)n0 * ldb;
  const int wid = tid >> 6, lane = tid & 63;
  const int wm = (wid & 1) << 5, wn = (wid >> 1) * (BN / 2);
  const int q = lane >> 4, r = lane & 15;
  constexpr int NJ = BN / 32;
  floatx4 acc[2][NJ] = {};
  const int arow = tid >> 3;        // 0..31
  const int acol = (tid & 7) << 3;  // 16B k-chunks
  for (int k0 = 0; k0 < K; k0 += 64) {
    __syncthreads();
#pragma unroll
    for (int rr = 0; rr < 2; rr++) {
      int row = arow + rr * 32;
      int gr = bm + row; if (gr >= M) gr = M - 1;
      *(uint4*)&Al[row][acol] = *(const uint4*)&Ab[(size_t)gr * lda + k0 + acol];
    }
#pragma unroll
    for (int rr = 0; rr < BN / 32; rr++) {
      int row = arow + rr * 32;
      *(uint4*)&Bl[row][acol] = *(const uint4*)&Bb[(size_t)row * ldb + k0 + acol];
    }
    __syncthreads();
#pragma unroll
    for (int kk = 0; kk < 64; kk += 32) {
      short8 af[2], bfr[NJ];
#pragma unroll
      for (int i = 0; i < 2; i++)  af[i]  = *(const short8*)&Al[wm + i * 16 + r][kk + q * 8];
#pragma unroll
      for (int j = 0; j < NJ; j++) bfr[j] = *(const short8*)&Bl[wn + j * 16 + r][kk + q * 8];
#pragma unroll
      for (int i = 0; i < 2; i++)
#pragma unroll
        for (int j = 0; j < NJ; j++)
          acc[i][j] = __builtin_amdgcn_mfma_f32_16x16x32_bf16(af[i], bfr[j], acc[i][j], 0, 0, 0);
    }
  }
  // C/D layout: col = lane&15 (n), row = quad*4 + reg (m)   [verified m89/m91]
#pragma unroll
  for (int i = 0; i < 2; i++)
#pragma unroll
    for (int j = 0; j < NJ; j++) {
      int gn = n0 + wn + j * 16 + r;
      float bv = bias[zBias * z + gn];
#pragma unroll
      for (int t2 = 0; t2 < 4; t2++) {
        int gm = bm + wm + i * 16 + q * 4 + t2;
        if (gm < M) {
          float v = acc[i][j][t2];
          if (EPI == 1) { v += bv; v = v > 0.f ? v : expm1f(v); }
          else          { v = v * 0.125f + bv; }
          C[(size_t)z * zC + (size_t)gm * ldc + gn] = v;
        }
      }
    }
}

extern "C" void kernel_launch(void* const* d_in, const int* in_sizes, int n_in,
                              void* d_out, int out_size, void* d_ws, size_t ws_size,
                              hipStream_t stream) {
  const float* x    = (const float*)d_in[0];
  const int* src1   = (const int*)d_in[1];
  const int* dst1   = (const int*)d_in[2];
  const int* src2   = (const int*)d_in[3];
  const int* dst2   = (const int*)d_in[4];
  const float* W1   = (const float*)d_in[5];
  const float* atts1 = (const float*)d_in[6];
  const float* attd1 = (const float*)d_in[7];
  const float* b1   = (const float*)d_in[8];
  const float* W2   = (const float*)d_in[9];
  const float* atts2 = (const float*)d_in[10];
  const float* attd2 = (const float*)d_in[11];
  const float* b2   = (const float*)d_in[12];
  const int E1 = in_sizes[1], E2 = in_sizes[3];

  uint8_t* p = (uint8_t*)d_ws;
  auto alloc = [&](size_t b) { uint8_t* r = p; p += (b + 255) & ~(size_t)255; return r; };
  // persistent (~52 MB)
  float* x1   = (float*)alloc((size_t)cN1 * cHC1 * 4);
  u16*   W1t  = (u16*)alloc((size_t)512 * 256 * 2);
  u16*   W2te = (u16*)alloc((size_t)256 * 4096 * 2);
  float* wts1 = (float*)alloc(8 * 256 * 4);
  float* wtd1 = (float*)alloc(8 * 256 * 4);
  float* wts2 = (float*)alloc(8 * 512 * 4);
  float* wtd2 = (float*)alloc(8 * 512 * 4);
  uint8_t* scratch = p;
  // phase A (~39 MB)
  u16*   aggA = (u16*)alloc((size_t)CH1 * 2048 * 2);
  float* a_s1 = (float*)alloc((size_t)cN0 * 32);
  float* a_d1 = (float*)alloc((size_t)cN1 * 32);
  float* ex1  = (float*)alloc((size_t)E1 * 32);
  int*   ids1 = (int*)alloc((size_t)E1 * 4);
  int*   off1 = (int*)alloc((size_t)(cN1 + 1) * 4);
  uint8_t* zA = p;
  float* den1 = (float*)alloc((size_t)cN1 * 32);
  int*   cnt1 = (int*)alloc((size_t)cN1 * 4);
  int*   cur1 = (int*)alloc((size_t)cN1 * 4);
  size_t zAbytes = (size_t)(p - zA);
  // phase B aliases phase A (~29 MB)
  p = scratch;
  u16*   aggB = (u16*)alloc((size_t)CH2 * 4096 * 2);
  float* a_s2 = (float*)alloc((size_t)cN1 * 32);
  float* a_d2 = (float*)alloc((size_t)cN2 * 32);
  float* ex2  = (float*)alloc((size_t)E2 * 32);
  int*   ids2 = (int*)alloc((size_t)E2 * 4);
  int*   off2 = (int*)alloc((size_t)(cN2 + 1) * 4);
  uint8_t* zB = p;
  float* den2 = (float*)alloc((size_t)cN2 * 32);
  int*   cnt2 = (int*)alloc((size_t)cN2 * 4);
  int*   cur2 = (int*)alloc((size_t)cN2 * 4);
  size_t zBbytes = (size_t)(p - zB);

  // ---- prep ----
  gat_w1t<<<(512 * 256 + 255) / 256, 256, 0, stream>>>(W1, W1t);
  gat_make_w2te<<<(256 * 4096 + 255) / 256, 256, 0, stream>>>(W2, W2te);
  gat_make_watt<<<1, 256, 0, stream>>>(W1, atts1, attd1, wts1, wtd1, 256, 64, 512);
  gat_make_watt<<<2, 256, 0, stream>>>(W2, atts2, attd2, wts2, wtd2, 512, 256, 2048);

  // ---- layer 1 ----
  hipMemsetAsync(zA, 0, zAbytes, stream);
  gat_scores<256><<<cN0 / 4, 256, 0, stream>>>(x, wts1, wtd1, a_s1, a_d1, cN0, cN1);
  gat_hist<<<(E1 + 255) / 256, 256, 0, stream>>>(dst1, cnt1, E1);
  gat_scan_excl<<<1, 1024, 0, stream>>>(cnt1, off1, cN1);
  gat_scatter<<<(E1 + 255) / 256, 256, 0, stream>>>(dst1, off1, cur1, ids1, E1);
  gat_edge_pass<<<(E1 + 255) / 256, 256, 0, stream>>>(src1, dst1, a_s1, a_d1, ex1, den1, E1);
  for (int c = 0; c < cN1 / CH1; c++) {
    int d0 = c * CH1;
    gat_gather_in1<<<CH1, 256, 0, stream>>>(x, ex1, den1, off1, ids1, src1, aggA, d0);
    gat_gemm<64, 1><<<dim3(CH1 / 64, 1, 8), 256, 0, stream>>>(
        aggA, 2048, W1t, 256, x1 + (size_t)d0 * cHC1, cHC1,
        CH1, 256, b1, /*zA*/256, /*zB*/64 * 256, /*zC*/64, /*zBias*/64);
  }

  // ---- layer 2 ----
  hipMemsetAsync(zB, 0, zBbytes, stream);
  gat_scores<512><<<cN1 / 4, 256, 0, stream>>>(x1, wts2, wtd2, a_s2, a_d2, cN1, cN2);
  gat_hist<<<(E2 + 255) / 256, 256, 0, stream>>>(dst2, cnt2, E2);
  gat_scan_excl<<<1, 1024, 0, stream>>>(cnt2, off2, cN2);
  gat_scatter<<<(E2 + 255) / 256, 256, 0, stream>>>(dst2, off2, cur2, ids2, E2);
  gat_edge_pass<<<(E2 + 255) / 256, 256, 0, stream>>>(src2, dst2, a_s2, a_d2, ex2, den2, E2);
  for (int c = 0; c < cN2 / CH2; c++) {
    int d0 = c * CH2;
    gat_gather_in2<<<CH2, 256, 0, stream>>>(x1, ex2, den2, off2, ids2, src2, aggB, d0);
    gat_gemm<128, 2><<<dim3((CH2 + 63) / 64, 2, 1), 256, 0, stream>>>(
        aggB, 4096, W2te, 4096, (float*)d_out + (size_t)d0 * 256, 256,
        CH2, 4096, b2, 0, 0, 0, 0);
  }
}

// Round 4
// 1163.439 us; speedup vs baseline: 1.2812x; 1.2812x over previous
//
#include <hip/hip_runtime.h>
#include <hip/hip_bf16.h>
#include <cstdint>

typedef __attribute__((ext_vector_type(8))) short short8;
typedef __attribute__((ext_vector_type(4))) float floatx4;
typedef __hip_bfloat16 bf16;
typedef unsigned short u16;

static constexpr int cN0 = 120000, cN1 = 24000, cN2 = 6000;
static constexpr int cD = 256, cHC1 = 512;
static constexpr int CH1 = 4800;   // layer-1 target chunk (5 chunks, %64==0)
static constexpr int CH2 = 3000;   // layer-2 target chunk (2 chunks, M-guarded)

// ---------- W1t[n*256+k] = bf16(W1[k*512+n]) ----------
__global__ __launch_bounds__(256)
void gat_w1t(const float* __restrict__ W1, u16* __restrict__ dst) {
  int t = blockIdx.x * 256 + threadIdx.x;  // t = n*256+k
  if (t >= 512 * 256) return;
  int n = t >> 8, k = t & 255;
  bf16 v = bf16(W1[(size_t)k * 512 + n]);
  dst[t] = *(u16*)&v;
}

// ---------- W2te[c*4096 + h*512 + k] = bf16(W2[k*2048 + h*256 + c]) ----------
// LDS-tiled: coalesced reads (c contiguous) and writes (k contiguous).
// grid: (512/32, 256/32, 8) = (16, 8, 8), block 256
__global__ __launch_bounds__(256)
void gat_make_w2te(const float* __restrict__ W2, u16* __restrict__ out) {
  __shared__ u16 tile[32][33];
  int kt = blockIdx.x * 32, ct = blockIdx.y * 32, h = blockIdx.z;
  int tx = threadIdx.x & 31, ty4 = (threadIdx.x >> 5) * 4;
#pragma unroll
  for (int i = 0; i < 4; i++) {
    int k = kt + ty4 + i, c = ct + tx;
    bf16 v = bf16(W2[(size_t)k * 2048 + h * 256 + c]);
    tile[ty4 + i][tx] = *(u16*)&v;
  }
  __syncthreads();
#pragma unroll
  for (int i = 0; i < 4; i++) {
    int c = ct + ty4 + i, k = kt + tx;
    out[(size_t)c * 4096 + h * 512 + k] = tile[tx][ty4 + i];
  }
}

// ---------- watt[h*K+k] = sum_c W[k*ldw + h*Ch + c] * att[h*Ch+c]  (f32) ----------
// one wave per (h,k) output; lanes coalesced over c; grid = 2*K blocks of 256
__global__ __launch_bounds__(256)
void gat_make_watt(const float* __restrict__ W, const float* __restrict__ atts,
                   const float* __restrict__ attd, float* __restrict__ ws,
                   float* __restrict__ wd, int K, int Ch, int ldw) {
  int lane = threadIdx.x & 63;
  int task = blockIdx.x * 4 + (threadIdx.x >> 6);  // task = h*K + k
  if (task >= 8 * K) return;
  int h = task / K, k = task - h * K;
  const float* Wr = W + (size_t)k * ldw + h * Ch;
  const float* as = atts + h * Ch;
  const float* ad = attd + h * Ch;
  float ss = 0.f, dd = 0.f;
  for (int c = lane; c < Ch; c += 64) {
    float wv = Wr[c];
    ss += wv * as[c];
    dd += wv * ad[c];
  }
#pragma unroll
  for (int o = 32; o; o >>= 1) { ss += __shfl_down(ss, o); dd += __shfl_down(dd, o); }
  if (lane == 0) { ws[task] = ss; wd[task] = dd; }
}

// ---------- a_s[n,h] = x[n,:] . watt_s[h,:]  (one wave per row) ----------
template<int K>
__global__ __launch_bounds__(256)
void gat_scores(const float* __restrict__ x, const float* __restrict__ wsrc,
                const float* __restrict__ wdst, float* __restrict__ a_s,
                float* __restrict__ a_d, int M, int MD) {
  constexpr int NK = K / 64;   // floats per lane: 4 or 8
  int lane = threadIdx.x & 63;
  int row = blockIdx.x * 4 + (threadIdx.x >> 6);
  if (row >= M) return;
  const float* xr = x + (size_t)row * K + lane * NK;
  float xv[NK];
#pragma unroll
  for (int j = 0; j < NK / 4; j++) {
    float4 v = ((const float4*)xr)[j];
    xv[4 * j] = v.x; xv[4 * j + 1] = v.y; xv[4 * j + 2] = v.z; xv[4 * j + 3] = v.w;
  }
  bool dodst = row < MD;
#pragma unroll
  for (int h = 0; h < 8; h++) {
    const float* wr  = wsrc + h * K + lane * NK;
    const float* wr2 = wdst + h * K + lane * NK;
    float v = 0.f, v2 = 0.f;
#pragma unroll
    for (int j = 0; j < NK / 4; j++) {
      float4 a = ((const float4*)wr)[j];
      float4 b = ((const float4*)wr2)[j];
      v  += xv[4*j]*a.x + xv[4*j+1]*a.y + xv[4*j+2]*a.z + xv[4*j+3]*a.w;
      v2 += xv[4*j]*b.x + xv[4*j+1]*b.y + xv[4*j+2]*b.z + xv[4*j+3]*b.w;
    }
#pragma unroll
    for (int o = 32; o; o >>= 1) { v += __shfl_down(v, o); v2 += __shfl_down(v2, o); }
    if (lane == 0) {
      a_s[row * 8 + h] = v;
      if (dodst) a_d[row * 8 + h] = v2;
    }
  }
}

// ---------- CSR build ----------
__global__ __launch_bounds__(256)
void gat_hist(const int* __restrict__ dstv, int* __restrict__ cnt, int E) {
  int t = blockIdx.x * 256 + threadIdx.x;
  if (t < E) atomicAdd(&cnt[dstv[t]], 1);
}

__global__ __launch_bounds__(1024)
void gat_scan_excl(const int* __restrict__ cnt, int* __restrict__ off, int n) {
  __shared__ int wsum[16];
  __shared__ int carry_s;
  int t = threadIdx.x, lane = t & 63, wid = t >> 6;
  if (t == 0) carry_s = 0;
  __syncthreads();
  for (int base = 0; base < n; base += 1024) {
    int idx = base + t;
    int v = (idx < n) ? cnt[idx] : 0;
    int x = v;
#pragma unroll
    for (int d = 1; d < 64; d <<= 1) { int y = __shfl_up(x, d); if (lane >= d) x += y; }
    if (lane == 63) wsum[wid] = x;
    __syncthreads();
    if (t < 16) {
      int s = wsum[t];
#pragma unroll
      for (int d = 1; d < 16; d <<= 1) { int y = __shfl_up(s, d); if (t >= d) s += y; }
      wsum[t] = s;
    }
    __syncthreads();
    int prefix = carry_s + (wid ? wsum[wid - 1] : 0) + x - v;
    if (idx < n) off[idx] = prefix;
    int tot = wsum[15];
    __syncthreads();
    if (t == 0) carry_s += tot;
    __syncthreads();
  }
  if (threadIdx.x == 0) off[n] = carry_s;
}

__global__ __launch_bounds__(256)
void gat_scatter(const int* __restrict__ dstv, const int* __restrict__ off,
                 int* __restrict__ cur, int* __restrict__ ids, int E) {
  int t = blockIdx.x * 256 + threadIdx.x;
  if (t < E) {
    int d = dstv[t];
    int p = atomicAdd(&cur[d], 1);
    ids[off[d] + p] = t;
  }
}

// ---------- ex = exp(leaky(a_src+a_dst)), denom += ex ----------
__global__ __launch_bounds__(256)
void gat_edge_pass(const int* __restrict__ src, const int* __restrict__ dstv,
                   const float* __restrict__ a_s, const float* __restrict__ a_d,
                   float* __restrict__ ex, float* __restrict__ denom, int E) {
  int t = blockIdx.x * 256 + threadIdx.x;
  if (t >= E) return;
  int s = src[t], d = dstv[t];
  const float* as = a_s + (size_t)s * 8;
  const float* ad = a_d + (size_t)d * 8;
  float4 s0 = *(const float4*)as, s1 = *(const float4*)(as + 4);
  float4 d0 = *(const float4*)ad, d1 = *(const float4*)(ad + 4);
  float ev[8] = { s0.x + d0.x, s0.y + d0.y, s0.z + d0.z, s0.w + d0.w,
                  s1.x + d1.x, s1.y + d1.y, s1.z + d1.z, s1.w + d1.w };
  float exv[8];
#pragma unroll
  for (int h = 0; h < 8; h++) {
    float e = ev[h];
    e = e > 0.f ? e : 0.2f * e;
    float xv = expf(e);   // shift-invariant softmax; |e| <~ 8 so no overflow
    exv[h] = xv;
    atomicAdd(&denom[(size_t)d * 8 + h], xv);
  }
  float4* op = (float4*)(ex + (size_t)t * 8);
  op[0] = make_float4(exv[0], exv[1], exv[2], exv[3]);
  op[1] = make_float4(exv[4], exv[5], exv[6], exv[7]);
}

// ---------- layer-1 input-space gather: agg[d,h,k] = sum alpha_h x[s,k] -> bf16 ----------
__global__ __launch_bounds__(256)
void gat_gather_in1(const float* __restrict__ x, const float* __restrict__ ex,
                    const float* __restrict__ den, const int* __restrict__ off,
                    const int* __restrict__ ids, const int* __restrict__ srcv,
                    u16* __restrict__ agg, int d0) {
  int d = d0 + blockIdx.x, t = threadIdx.x;  // t = k (0..255)
  int beg = off[d], end = off[d + 1];
  float inv[8];
#pragma unroll
  for (int j = 0; j < 8; j++) inv[j] = 1.f / den[(size_t)d * 8 + j];
  float acc[8] = {};
  int e_n = 0, s_n = 0;
  if (beg < end) { e_n = ids[beg]; s_n = srcv[e_n]; }
  for (int i = beg; i < end; i++) {
    int e = e_n, s = s_n;
    if (i + 1 < end) { e_n = ids[i + 1]; s_n = srcv[e_n]; }
    float4 e0 = *(const float4*)&ex[(size_t)e * 8];
    float4 e1 = *(const float4*)&ex[(size_t)e * 8 + 4];
    float xv = x[(size_t)s * cD + t];
    acc[0] += e0.x * inv[0] * xv; acc[1] += e0.y * inv[1] * xv;
    acc[2] += e0.z * inv[2] * xv; acc[3] += e0.w * inv[3] * xv;
    acc[4] += e1.x * inv[4] * xv; acc[5] += e1.y * inv[5] * xv;
    acc[6] += e1.z * inv[6] * xv; acc[7] += e1.w * inv[7] * xv;
  }
  u16* ap = agg + (size_t)blockIdx.x * 2048 + t;
#pragma unroll
  for (int j = 0; j < 8; j++) {
    bf16 v = bf16(acc[j]);
    ap[(size_t)j * 256] = *(u16*)&v;
  }
}

// ---------- layer-2 input-space gather: agg[d,h,k] (k<512) -> bf16 ----------
__global__ __launch_bounds__(256)
void gat_gather_in2(const float* __restrict__ x1, const float* __restrict__ ex,
                    const float* __restrict__ den, const int* __restrict__ off,
                    const int* __restrict__ ids, const int* __restrict__ srcv,
                    u16* __restrict__ agg, int d0) {
  int d = d0 + blockIdx.x, t = threadIdx.x;  // k pair: t, t+256
  int beg = off[d], end = off[d + 1];
  float inv[8];
#pragma unroll
  for (int j = 0; j < 8; j++) inv[j] = 1.f / den[(size_t)d * 8 + j];
  float acc0[8] = {}, acc1[8] = {};
  int e_n = 0, s_n = 0;
  if (beg < end) { e_n = ids[beg]; s_n = srcv[e_n]; }
  for (int i = beg; i < end; i++) {
    int e = e_n, s = s_n;
    if (i + 1 < end) { e_n = ids[i + 1]; s_n = srcv[e_n]; }
    float4 e0 = *(const float4*)&ex[(size_t)e * 8];
    float4 e1 = *(const float4*)&ex[(size_t)e * 8 + 4];
    float al[8] = { e0.x * inv[0], e0.y * inv[1], e0.z * inv[2], e0.w * inv[3],
                    e1.x * inv[4], e1.y * inv[5], e1.z * inv[6], e1.w * inv[7] };
    float xv0 = x1[(size_t)s * cHC1 + t];
    float xv1 = x1[(size_t)s * cHC1 + t + 256];
#pragma unroll
    for (int j = 0; j < 8; j++) { acc0[j] += al[j] * xv0; acc1[j] += al[j] * xv1; }
  }
  u16* ap = agg + (size_t)blockIdx.x * 4096;
#pragma unroll
  for (int j = 0; j < 8; j++) {
    bf16 v0 = bf16(acc0[j]), v1 = bf16(acc1[j]);
    ap[(size_t)j * 512 + t]       = *(u16*)&v0;
    ap[(size_t)j * 512 + t + 256] = *(u16*)&v1;
  }
}

// ---------- GEMM: C = A[M,K] @ Bt[N,K]^T (bf16 in, f32 out), M-guarded, fused epilogue ----------
// EPI=1: elu(v+bias) (layer-1 x1); EPI=2: v*0.125+bias (layer-2 out)
template<int BN, int EPI>
__global__ __launch_bounds__(256)
void gat_gemm(const u16* __restrict__ A, long lda, const u16* __restrict__ Bt, long ldb,
              float* __restrict__ C, long ldc, int M, int K,
              const float* __restrict__ bias, int zA, int zB, int zC, int zBias) {
  __shared__ __align__(16) u16 Al[64][72];   // +8 pad
  __shared__ __align__(16) u16 Bl[BN][72];
  const int tid = threadIdx.x;
  const int bm = blockIdx.x << 6;
  const int n0 = blockIdx.y * BN;
  const int z = blockIdx.z;
  const u16* Ab = A + (size_t)z * zA;
  const u16* Bb = Bt + (size_t)z * zB + (size_t)n0 * ldb;
  const int wid = tid >> 6, lane = tid & 63;
  const int wm = (wid & 1) << 5, wn = (wid >> 1) * (BN / 2);
  const int q = lane >> 4, r = lane & 15;
  constexpr int NJ = BN / 32;
  floatx4 acc[2][NJ] = {};
  const int arow = tid >> 3;        // 0..31
  const int acol = (tid & 7) << 3;  // 16B k-chunks
  for (int k0 = 0; k0 < K; k0 += 64) {
    __syncthreads();
#pragma unroll
    for (int rr = 0; rr < 2; rr++) {
      int row = arow + rr * 32;
      int gr = bm + row; if (gr >= M) gr = M - 1;
      *(uint4*)&Al[row][acol] = *(const uint4*)&Ab[(size_t)gr * lda + k0 + acol];
    }
#pragma unroll
    for (int rr = 0; rr < BN / 32; rr++) {
      int row = arow + rr * 32;
      *(uint4*)&Bl[row][acol] = *(const uint4*)&Bb[(size_t)row * ldb + k0 + acol];
    }
    __syncthreads();
#pragma unroll
    for (int kk = 0; kk < 64; kk += 32) {
      short8 af[2], bfr[NJ];
#pragma unroll
      for (int i = 0; i < 2; i++)  af[i]  = *(const short8*)&Al[wm + i * 16 + r][kk + q * 8];
#pragma unroll
      for (int j = 0; j < NJ; j++) bfr[j] = *(const short8*)&Bl[wn + j * 16 + r][kk + q * 8];
#pragma unroll
      for (int i = 0; i < 2; i++)
#pragma unroll
        for (int j = 0; j < NJ; j++)
          acc[i][j] = __builtin_amdgcn_mfma_f32_16x16x32_bf16(af[i], bfr[j], acc[i][j], 0, 0, 0);
    }
  }
  // C/D layout: col = lane&15 (n), row = quad*4 + reg (m)   [verified m89/m91]
#pragma unroll
  for (int i = 0; i < 2; i++)
#pragma unroll
    for (int j = 0; j < NJ; j++) {
      int gn = n0 + wn + j * 16 + r;
      float bv = bias[zBias * z + gn];
#pragma unroll
      for (int t2 = 0; t2 < 4; t2++) {
        int gm = bm + wm + i * 16 + q * 4 + t2;
        if (gm < M) {
          float v = acc[i][j][t2];
          if (EPI == 1) { v += bv; v = v > 0.f ? v : expm1f(v); }
          else          { v = v * 0.125f + bv; }
          C[(size_t)z * zC + (size_t)gm * ldc + gn] = v;
        }
      }
    }
}

extern "C" void kernel_launch(void* const* d_in, const int* in_sizes, int n_in,
                              void* d_out, int out_size, void* d_ws, size_t ws_size,
                              hipStream_t stream) {
  const float* x    = (const float*)d_in[0];
  const int* src1   = (const int*)d_in[1];
  const int* dst1   = (const int*)d_in[2];
  const int* src2   = (const int*)d_in[3];
  const int* dst2   = (const int*)d_in[4];
  const float* W1   = (const float*)d_in[5];
  const float* atts1 = (const float*)d_in[6];
  const float* attd1 = (const float*)d_in[7];
  const float* b1   = (const float*)d_in[8];
  const float* W2   = (const float*)d_in[9];
  const float* atts2 = (const float*)d_in[10];
  const float* attd2 = (const float*)d_in[11];
  const float* b2   = (const float*)d_in[12];
  const int E1 = in_sizes[1], E2 = in_sizes[3];

  uint8_t* p = (uint8_t*)d_ws;
  auto alloc = [&](size_t b) { uint8_t* r = p; p += (b + 255) & ~(size_t)255; return r; };
  // persistent (~52 MB)
  float* x1   = (float*)alloc((size_t)cN1 * cHC1 * 4);
  u16*   W1t  = (u16*)alloc((size_t)512 * 256 * 2);
  u16*   W2te = (u16*)alloc((size_t)256 * 4096 * 2);
  float* wts1 = (float*)alloc(8 * 256 * 4);
  float* wtd1 = (float*)alloc(8 * 256 * 4);
  float* wts2 = (float*)alloc(8 * 512 * 4);
  float* wtd2 = (float*)alloc(8 * 512 * 4);
  uint8_t* scratch = p;
  // phase A (~39 MB)
  u16*   aggA = (u16*)alloc((size_t)CH1 * 2048 * 2);
  float* a_s1 = (float*)alloc((size_t)cN0 * 32);
  float* a_d1 = (float*)alloc((size_t)cN1 * 32);
  float* ex1  = (float*)alloc((size_t)E1 * 32);
  int*   ids1 = (int*)alloc((size_t)E1 * 4);
  int*   off1 = (int*)alloc((size_t)(cN1 + 1) * 4);
  uint8_t* zA = p;
  float* den1 = (float*)alloc((size_t)cN1 * 32);
  int*   cnt1 = (int*)alloc((size_t)cN1 * 4);
  int*   cur1 = (int*)alloc((size_t)cN1 * 4);
  size_t zAbytes = (size_t)(p - zA);
  // phase B aliases phase A (~29 MB)
  p = scratch;
  u16*   aggB = (u16*)alloc((size_t)CH2 * 4096 * 2);
  float* a_s2 = (float*)alloc((size_t)cN1 * 32);
  float* a_d2 = (float*)alloc((size_t)cN2 * 32);
  float* ex2  = (float*)alloc((size_t)E2 * 32);
  int*   ids2 = (int*)alloc((size_t)E2 * 4);
  int*   off2 = (int*)alloc((size_t)(cN2 + 1) * 4);
  uint8_t* zB = p;
  float* den2 = (float*)alloc((size_t)cN2 * 32);
  int*   cnt2 = (int*)alloc((size_t)cN2 * 4);
  int*   cur2 = (int*)alloc((size_t)cN2 * 4);
  size_t zBbytes = (size_t)(p - zB);

  // ---- prep ----
  gat_w1t<<<(512 * 256 + 255) / 256, 256, 0, stream>>>(W1, W1t);
  gat_make_w2te<<<dim3(16, 8, 8), 256, 0, stream>>>(W2, W2te);
  gat_make_watt<<<2 * 256, 256, 0, stream>>>(W1, atts1, attd1, wts1, wtd1, 256, 64, 512);
  gat_make_watt<<<2 * 512, 256, 0, stream>>>(W2, atts2, attd2, wts2, wtd2, 512, 256, 2048);

  // ---- layer 1 ----
  hipMemsetAsync(zA, 0, zAbytes, stream);
  gat_scores<256><<<cN0 / 4, 256, 0, stream>>>(x, wts1, wtd1, a_s1, a_d1, cN0, cN1);
  gat_hist<<<(E1 + 255) / 256, 256, 0, stream>>>(dst1, cnt1, E1);
  gat_scan_excl<<<1, 1024, 0, stream>>>(cnt1, off1, cN1);
  gat_scatter<<<(E1 + 255) / 256, 256, 0, stream>>>(dst1, off1, cur1, ids1, E1);
  gat_edge_pass<<<(E1 + 255) / 256, 256, 0, stream>>>(src1, dst1, a_s1, a_d1, ex1, den1, E1);
  for (int c = 0; c < cN1 / CH1; c++) {
    int d0 = c * CH1;
    gat_gather_in1<<<CH1, 256, 0, stream>>>(x, ex1, den1, off1, ids1, src1, aggA, d0);
    gat_gemm<64, 1><<<dim3(CH1 / 64, 1, 8), 256, 0, stream>>>(
        aggA, 2048, W1t, 256, x1 + (size_t)d0 * cHC1, cHC1,
        CH1, 256, b1, /*zA*/256, /*zB*/64 * 256, /*zC*/64, /*zBias*/64);
  }

  // ---- layer 2 ----
  hipMemsetAsync(zB, 0, zBbytes, stream);
  gat_scores<512><<<cN1 / 4, 256, 0, stream>>>(x1, wts2, wtd2, a_s2, a_d2, cN1, cN2);
  gat_hist<<<(E2 + 255) / 256, 256, 0, stream>>>(dst2, cnt2, E2);
  gat_scan_excl<<<1, 1024, 0, stream>>>(cnt2, off2, cN2);
  gat_scatter<<<(E2 + 255) / 256, 256, 0, stream>>>(dst2, off2, cur2, ids2, E2);
  gat_edge_pass<<<(E2 + 255) / 256, 256, 0, stream>>>(src2, dst2, a_s2, a_d2, ex2, den2, E2);
  for (int c = 0; c < cN2 / CH2; c++) {
    int d0 = c * CH2;
    gat_gather_in2<<<CH2, 256, 0, stream>>>(x1, ex2, den2, off2, ids2, src2, aggB, d0);
    gat_gemm<128, 2><<<dim3((CH2 + 63) / 64, 2, 1), 256, 0, stream>>>(
        aggB, 4096, W2te, 4096, (float*)d_out + (size_t)d0 * 256, 256,
        CH2, 4096, b2, 0, 0, 0, 0);
  }
}

// Round 5
// 950.743 us; speedup vs baseline: 1.5678x; 1.2237x over previous
//
#include <hip/hip_runtime.h>
#include <hip/hip_bf16.h>
#include <cstdint>

typedef __attribute__((ext_vector_type(8))) short short8;
typedef __attribute__((ext_vector_type(4))) float floatx4;
typedef __hip_bfloat16 bf16;
typedef unsigned short u16;

static constexpr int cN0 = 120000, cN1 = 24000, cN2 = 6000;
static constexpr int cD = 256, cHC1 = 512;
static constexpr int CH1 = 4800;   // layer-1 target chunk (5 chunks, %64==0)
static constexpr int CH2 = 3000;   // layer-2 target chunk (2 chunks, M-guarded)

// ---------- W1t[n*256+k] = bf16(W1[k*512+n]) ----------
__global__ __launch_bounds__(256)
void gat_w1t(const float* __restrict__ W1, u16* __restrict__ dst) {
  int t = blockIdx.x * 256 + threadIdx.x;  // t = n*256+k
  if (t >= 512 * 256) return;
  int n = t >> 8, k = t & 255;
  bf16 v = bf16(W1[(size_t)k * 512 + n]);
  dst[t] = *(u16*)&v;
}

// ---------- W2te[c*4096 + h*512 + k] = bf16(W2[k*2048 + h*256 + c]) ----------
__global__ __launch_bounds__(256)
void gat_make_w2te(const float* __restrict__ W2, u16* __restrict__ out) {
  __shared__ u16 tile[32][33];
  int kt = blockIdx.x * 32, ct = blockIdx.y * 32, h = blockIdx.z;
  int tx = threadIdx.x & 31, ty4 = (threadIdx.x >> 5) * 4;
#pragma unroll
  for (int i = 0; i < 4; i++) {
    int k = kt + ty4 + i, c = ct + tx;
    bf16 v = bf16(W2[(size_t)k * 2048 + h * 256 + c]);
    tile[ty4 + i][tx] = *(u16*)&v;
  }
  __syncthreads();
#pragma unroll
  for (int i = 0; i < 4; i++) {
    int c = ct + ty4 + i, k = kt + tx;
    out[(size_t)c * 4096 + h * 512 + k] = tile[tx][ty4 + i];
  }
}

// ---------- watt[h*K+k] = sum_c W[k*ldw + h*Ch + c] * att[h*Ch+c]  (f32) ----------
__global__ __launch_bounds__(256)
void gat_make_watt(const float* __restrict__ W, const float* __restrict__ atts,
                   const float* __restrict__ attd, float* __restrict__ ws,
                   float* __restrict__ wd, int K, int Ch, int ldw) {
  int lane = threadIdx.x & 63;
  int task = blockIdx.x * 4 + (threadIdx.x >> 6);  // task = h*K + k
  if (task >= 8 * K) return;
  int h = task / K, k = task - h * K;
  const float* Wr = W + (size_t)k * ldw + h * Ch;
  const float* as = atts + h * Ch;
  const float* ad = attd + h * Ch;
  float ss = 0.f, dd = 0.f;
  for (int c = lane; c < Ch; c += 64) {
    float wv = Wr[c];
    ss += wv * as[c];
    dd += wv * ad[c];
  }
#pragma unroll
  for (int o = 32; o; o >>= 1) { ss += __shfl_down(ss, o); dd += __shfl_down(dd, o); }
  if (lane == 0) { ws[task] = ss; wd[task] = dd; }
}

// ---------- a_s[n,h] = x[n,:] . watt_s[h,:]  (one wave per row) ----------
template<int K>
__global__ __launch_bounds__(256)
void gat_scores(const float* __restrict__ x, const float* __restrict__ wsrc,
                const float* __restrict__ wdst, float* __restrict__ a_s,
                float* __restrict__ a_d, int M, int MD) {
  constexpr int NK = K / 64;   // floats per lane: 4 or 8
  int lane = threadIdx.x & 63;
  int row = blockIdx.x * 4 + (threadIdx.x >> 6);
  if (row >= M) return;
  const float* xr = x + (size_t)row * K + lane * NK;
  float xv[NK];
#pragma unroll
  for (int j = 0; j < NK / 4; j++) {
    float4 v = ((const float4*)xr)[j];
    xv[4 * j] = v.x; xv[4 * j + 1] = v.y; xv[4 * j + 2] = v.z; xv[4 * j + 3] = v.w;
  }
  bool dodst = row < MD;
#pragma unroll
  for (int h = 0; h < 8; h++) {
    const float* wr  = wsrc + h * K + lane * NK;
    const float* wr2 = wdst + h * K + lane * NK;
    float v = 0.f, v2 = 0.f;
#pragma unroll
    for (int j = 0; j < NK / 4; j++) {
      float4 a = ((const float4*)wr)[j];
      float4 b = ((const float4*)wr2)[j];
      v  += xv[4*j]*a.x + xv[4*j+1]*a.y + xv[4*j+2]*a.z + xv[4*j+3]*a.w;
      v2 += xv[4*j]*b.x + xv[4*j+1]*b.y + xv[4*j+2]*b.z + xv[4*j+3]*b.w;
    }
#pragma unroll
    for (int o = 32; o; o >>= 1) { v += __shfl_down(v, o); v2 += __shfl_down(v2, o); }
    if (lane == 0) {
      a_s[row * 8 + h] = v;
      if (dodst) a_d[row * 8 + h] = v2;
    }
  }
}

// ---------- CSR build ----------
__global__ __launch_bounds__(256)
void gat_hist(const int* __restrict__ dstv, int* __restrict__ cnt, int E) {
  int t = blockIdx.x * 256 + threadIdx.x;
  if (t < E) atomicAdd(&cnt[dstv[t]], 1);
}

__global__ __launch_bounds__(1024)
void gat_scan_excl(const int* __restrict__ cnt, int* __restrict__ off, int n) {
  __shared__ int wsum[16];
  __shared__ int carry_s;
  int t = threadIdx.x, lane = t & 63, wid = t >> 6;
  if (t == 0) carry_s = 0;
  __syncthreads();
  for (int base = 0; base < n; base += 1024) {
    int idx = base + t;
    int v = (idx < n) ? cnt[idx] : 0;
    int x = v;
#pragma unroll
    for (int d = 1; d < 64; d <<= 1) { int y = __shfl_up(x, d); if (lane >= d) x += y; }
    if (lane == 63) wsum[wid] = x;
    __syncthreads();
    if (t < 16) {
      int s = wsum[t];
#pragma unroll
      for (int d = 1; d < 16; d <<= 1) { int y = __shfl_up(s, d); if (t >= d) s += y; }
      wsum[t] = s;
    }
    __syncthreads();
    int prefix = carry_s + (wid ? wsum[wid - 1] : 0) + x - v;
    if (idx < n) off[idx] = prefix;
    int tot = wsum[15];
    __syncthreads();
    if (t == 0) carry_s += tot;
    __syncthreads();
  }
  if (threadIdx.x == 0) off[n] = carry_s;
}

// ---------- fused scatter+edge: claim CSR slot, write src & exp(leaky(e)) in slot order ----------
__global__ __launch_bounds__(256)
void gat_scatter_edge(const int* __restrict__ src, const int* __restrict__ dstv,
                      const float* __restrict__ a_s, const float* __restrict__ a_d,
                      const int* __restrict__ off, int* __restrict__ cur,
                      int* __restrict__ srcs, float* __restrict__ exs, int E) {
  int t = blockIdx.x * 256 + threadIdx.x;
  if (t >= E) return;
  int s = src[t], d = dstv[t];
  int slot = off[d] + atomicAdd(&cur[d], 1);
  srcs[slot] = s;
  const float* as = a_s + (size_t)s * 8;
  const float* ad = a_d + (size_t)d * 8;
  float4 s0 = *(const float4*)as, s1 = *(const float4*)(as + 4);
  float4 d0 = *(const float4*)ad, d1 = *(const float4*)(ad + 4);
  float ev[8] = { s0.x + d0.x, s0.y + d0.y, s0.z + d0.z, s0.w + d0.w,
                  s1.x + d1.x, s1.y + d1.y, s1.z + d1.z, s1.w + d1.w };
  float exv[8];
#pragma unroll
  for (int h = 0; h < 8; h++) {
    float e = ev[h];
    e = e > 0.f ? e : 0.2f * e;
    exv[h] = expf(e);  // shift-invariant softmax; |e| <~ 8 so no overflow
  }
  float4* op = (float4*)(exs + (size_t)slot * 8);
  op[0] = make_float4(exv[0], exv[1], exv[2], exv[3]);
  op[1] = make_float4(exv[4], exv[5], exv[6], exv[7]);
}

// ---------- per-dst denominators from slot-ordered exs (no atomics) ----------
__global__ __launch_bounds__(256)
void gat_denom(const float* __restrict__ exs, const int* __restrict__ off,
               float* __restrict__ den, int N) {
  int lane = threadIdx.x & 63;
  int d = blockIdx.x * 4 + (threadIdx.x >> 6);
  if (d >= N) return;
  int beg = off[d], end = off[d + 1];
  float s = 0.f;
  // element classes: (beg*8 + lane) & 7 == lane & 7 (stride 64 preserves head)
  for (size_t idx = (size_t)beg * 8 + lane; idx < (size_t)end * 8; idx += 64)
    s += exs[idx];
#pragma unroll
  for (int o = 32; o >= 8; o >>= 1) s += __shfl_down(s, o);
  if (lane < 8) den[(size_t)d * 8 + lane] = s;
}

// ---------- layer-1 input-space gather: agg[d,h,k] = sum alpha_h x[s,k] -> bf16 ----------
__global__ __launch_bounds__(256)
void gat_gather_in1(const float* __restrict__ x, const float* __restrict__ exs,
                    const float* __restrict__ den, const int* __restrict__ off,
                    const int* __restrict__ srcs, u16* __restrict__ agg, int d0) {
  int d = d0 + blockIdx.x, t = threadIdx.x;  // t = k (0..255)
  int beg = off[d], end = off[d + 1];
  float inv[8];
#pragma unroll
  for (int j = 0; j < 8; j++) inv[j] = 1.f / den[(size_t)d * 8 + j];
  float acc[8] = {};
  int s_n = 0;
  if (beg < end) s_n = srcs[beg];
  for (int i = beg; i < end; i++) {
    int s = s_n;
    if (i + 1 < end) s_n = srcs[i + 1];
    float4 e0 = *(const float4*)&exs[(size_t)i * 8];
    float4 e1 = *(const float4*)&exs[(size_t)i * 8 + 4];
    float xv = x[(size_t)s * cD + t];
    acc[0] += e0.x * inv[0] * xv; acc[1] += e0.y * inv[1] * xv;
    acc[2] += e0.z * inv[2] * xv; acc[3] += e0.w * inv[3] * xv;
    acc[4] += e1.x * inv[4] * xv; acc[5] += e1.y * inv[5] * xv;
    acc[6] += e1.z * inv[6] * xv; acc[7] += e1.w * inv[7] * xv;
  }
  u16* ap = agg + (size_t)blockIdx.x * 2048 + t;
#pragma unroll
  for (int j = 0; j < 8; j++) {
    bf16 v = bf16(acc[j]);
    ap[(size_t)j * 256] = *(u16*)&v;
  }
}

// ---------- layer-2 input-space gather: agg[d,h,k] (k<512) -> bf16 ----------
__global__ __launch_bounds__(256)
void gat_gather_in2(const float* __restrict__ x1, const float* __restrict__ exs,
                    const float* __restrict__ den, const int* __restrict__ off,
                    const int* __restrict__ srcs, u16* __restrict__ agg, int d0) {
  int d = d0 + blockIdx.x, t = threadIdx.x;  // k pair: t, t+256
  int beg = off[d], end = off[d + 1];
  float inv[8];
#pragma unroll
  for (int j = 0; j < 8; j++) inv[j] = 1.f / den[(size_t)d * 8 + j];
  float acc0[8] = {}, acc1[8] = {};
  int s_n = 0;
  if (beg < end) s_n = srcs[beg];
  for (int i = beg; i < end; i++) {
    int s = s_n;
    if (i + 1 < end) s_n = srcs[i + 1];
    float4 e0 = *(const float4*)&exs[(size_t)i * 8];
    float4 e1 = *(const float4*)&exs[(size_t)i * 8 + 4];
    float al[8] = { e0.x * inv[0], e0.y * inv[1], e0.z * inv[2], e0.w * inv[3],
                    e1.x * inv[4], e1.y * inv[5], e1.z * inv[6], e1.w * inv[7] };
    float xv0 = x1[(size_t)s * cHC1 + t];
    float xv1 = x1[(size_t)s * cHC1 + t + 256];
#pragma unroll
    for (int j = 0; j < 8; j++) { acc0[j] += al[j] * xv0; acc1[j] += al[j] * xv1; }
  }
  u16* ap = agg + (size_t)blockIdx.x * 4096;
#pragma unroll
  for (int j = 0; j < 8; j++) {
    bf16 v0 = bf16(acc0[j]), v1 = bf16(acc1[j]);
    ap[(size_t)j * 512 + t]       = *(u16*)&v0;
    ap[(size_t)j * 512 + t + 256] = *(u16*)&v1;
  }
}

// ---------- GEMM: C = A[M,K] @ Bt[N,K]^T (bf16 in, f32 out), M-guarded, fused epilogue ----------
template<int BN, int EPI>
__global__ __launch_bounds__(256)
void gat_gemm(const u16* __restrict__ A, long lda, const u16* __restrict__ Bt, long ldb,
              float* __restrict__ C, long ldc, int M, int K,
              const float* __restrict__ bias, int zA, int zB, int zC, int zBias) {
  __shared__ __align__(16) u16 Al[64][72];   // +8 pad
  __shared__ __align__(16) u16 Bl[BN][72];
  const int tid = threadIdx.x;
  const int bm = blockIdx.x << 6;
  const int n0 = blockIdx.y * BN;
  const int z = blockIdx.z;
  const u16* Ab = A + (size_t)z * zA;
  const u16* Bb = Bt + (size_t)z * zB + (size_t)n0 * ldb;
  const int wid = tid >> 6, lane = tid & 63;
  const int wm = (wid & 1) << 5, wn = (wid >> 1) * (BN / 2);
  const int q = lane >> 4, r = lane & 15;
  constexpr int NJ = BN / 32;
  floatx4 acc[2][NJ] = {};
  const int arow = tid >> 3;        // 0..31
  const int acol = (tid & 7) << 3;  // 16B k-chunks
  for (int k0 = 0; k0 < K; k0 += 64) {
    __syncthreads();
#pragma unroll
    for (int rr = 0; rr < 2; rr++) {
      int row = arow + rr * 32;
      int gr = bm + row; if (gr >= M) gr = M - 1;
      *(uint4*)&Al[row][acol] = *(const uint4*)&Ab[(size_t)gr * lda + k0 + acol];
    }
#pragma unroll
    for (int rr = 0; rr < BN / 32; rr++) {
      int row = arow + rr * 32;
      *(uint4*)&Bl[row][acol] = *(const uint4*)&Bb[(size_t)row * ldb + k0 + acol];
    }
    __syncthreads();
#pragma unroll
    for (int kk = 0; kk < 64; kk += 32) {
      short8 af[2], bfr[NJ];
#pragma unroll
      for (int i = 0; i < 2; i++)  af[i]  = *(const short8*)&Al[wm + i * 16 + r][kk + q * 8];
#pragma unroll
      for (int j = 0; j < NJ; j++) bfr[j] = *(const short8*)&Bl[wn + j * 16 + r][kk + q * 8];
#pragma unroll
      for (int i = 0; i < 2; i++)
#pragma unroll
        for (int j = 0; j < NJ; j++)
          acc[i][j] = __builtin_amdgcn_mfma_f32_16x16x32_bf16(af[i], bfr[j], acc[i][j], 0, 0, 0);
    }
  }
  // C/D layout: col = lane&15 (n), row = quad*4 + reg (m)   [verified m89/m91]
#pragma unroll
  for (int i = 0; i < 2; i++)
#pragma unroll
    for (int j = 0; j < NJ; j++) {
      int gn = n0 + wn + j * 16 + r;
      float bv = bias[zBias * z + gn];
#pragma unroll
      for (int t2 = 0; t2 < 4; t2++) {
        int gm = bm + wm + i * 16 + q * 4 + t2;
        if (gm < M) {
          float v = acc[i][j][t2];
          if (EPI == 1) { v += bv; v = v > 0.f ? v : expm1f(v); }
          else          { v = v * 0.125f + bv; }
          C[(size_t)z * zC + (size_t)gm * ldc + gn] = v;
        }
      }
    }
}

extern "C" void kernel_launch(void* const* d_in, const int* in_sizes, int n_in,
                              void* d_out, int out_size, void* d_ws, size_t ws_size,
                              hipStream_t stream) {
  const float* x    = (const float*)d_in[0];
  const int* src1   = (const int*)d_in[1];
  const int* dst1   = (const int*)d_in[2];
  const int* src2   = (const int*)d_in[3];
  const int* dst2   = (const int*)d_in[4];
  const float* W1   = (const float*)d_in[5];
  const float* atts1 = (const float*)d_in[6];
  const float* attd1 = (const float*)d_in[7];
  const float* b1   = (const float*)d_in[8];
  const float* W2   = (const float*)d_in[9];
  const float* atts2 = (const float*)d_in[10];
  const float* attd2 = (const float*)d_in[11];
  const float* b2   = (const float*)d_in[12];
  const int E1 = in_sizes[1], E2 = in_sizes[3];

  uint8_t* p = (uint8_t*)d_ws;
  auto alloc = [&](size_t b) { uint8_t* r = p; p += (b + 255) & ~(size_t)255; return r; };
  // persistent (~52 MB)
  float* x1   = (float*)alloc((size_t)cN1 * cHC1 * 4);
  u16*   W1t  = (u16*)alloc((size_t)512 * 256 * 2);
  u16*   W2te = (u16*)alloc((size_t)256 * 4096 * 2);
  float* wts1 = (float*)alloc(8 * 256 * 4);
  float* wtd1 = (float*)alloc(8 * 256 * 4);
  float* wts2 = (float*)alloc(8 * 512 * 4);
  float* wtd2 = (float*)alloc(8 * 512 * 4);
  uint8_t* scratch = p;
  // phase A
  u16*   aggA  = (u16*)alloc((size_t)CH1 * 2048 * 2);
  float* a_s1  = (float*)alloc((size_t)cN0 * 32);
  float* a_d1  = (float*)alloc((size_t)cN1 * 32);
  float* exs1  = (float*)alloc((size_t)E1 * 32);
  int*   srcs1 = (int*)alloc((size_t)E1 * 4);
  int*   off1  = (int*)alloc((size_t)(cN1 + 1) * 4);
  float* den1  = (float*)alloc((size_t)cN1 * 32);
  uint8_t* zA = p;
  int*   cnt1 = (int*)alloc((size_t)cN1 * 4);
  int*   cur1 = (int*)alloc((size_t)cN1 * 4);
  size_t zAbytes = (size_t)(p - zA);
  // phase B aliases phase A
  p = scratch;
  u16*   aggB  = (u16*)alloc((size_t)CH2 * 4096 * 2);
  float* a_s2  = (float*)alloc((size_t)cN1 * 32);
  float* a_d2  = (float*)alloc((size_t)cN2 * 32);
  float* exs2  = (float*)alloc((size_t)E2 * 32);
  int*   srcs2 = (int*)alloc((size_t)E2 * 4);
  int*   off2  = (int*)alloc((size_t)(cN2 + 1) * 4);
  float* den2  = (float*)alloc((size_t)cN2 * 32);
  uint8_t* zB = p;
  int*   cnt2 = (int*)alloc((size_t)cN2 * 4);
  int*   cur2 = (int*)alloc((size_t)cN2 * 4);
  size_t zBbytes = (size_t)(p - zB);

  // ---- prep ----
  gat_w1t<<<(512 * 256 + 255) / 256, 256, 0, stream>>>(W1, W1t);
  gat_make_w2te<<<dim3(16, 8, 8), 256, 0, stream>>>(W2, W2te);
  gat_make_watt<<<2 * 256, 256, 0, stream>>>(W1, atts1, attd1, wts1, wtd1, 256, 64, 512);
  gat_make_watt<<<2 * 512, 256, 0, stream>>>(W2, atts2, attd2, wts2, wtd2, 512, 256, 2048);

  // ---- layer 1 ----
  hipMemsetAsync(zA, 0, zAbytes, stream);
  gat_scores<256><<<cN0 / 4, 256, 0, stream>>>(x, wts1, wtd1, a_s1, a_d1, cN0, cN1);
  gat_hist<<<(E1 + 255) / 256, 256, 0, stream>>>(dst1, cnt1, E1);
  gat_scan_excl<<<1, 1024, 0, stream>>>(cnt1, off1, cN1);
  gat_scatter_edge<<<(E1 + 255) / 256, 256, 0, stream>>>(src1, dst1, a_s1, a_d1, off1, cur1, srcs1, exs1, E1);
  gat_denom<<<(cN1 + 3) / 4, 256, 0, stream>>>(exs1, off1, den1, cN1);
  for (int c = 0; c < cN1 / CH1; c++) {
    int d0 = c * CH1;
    gat_gather_in1<<<CH1, 256, 0, stream>>>(x, exs1, den1, off1, srcs1, aggA, d0);
    gat_gemm<64, 1><<<dim3(CH1 / 64, 1, 8), 256, 0, stream>>>(
        aggA, 2048, W1t, 256, x1 + (size_t)d0 * cHC1, cHC1,
        CH1, 256, b1, /*zA*/256, /*zB*/64 * 256, /*zC*/64, /*zBias*/64);
  }

  // ---- layer 2 ----
  hipMemsetAsync(zB, 0, zBbytes, stream);
  gat_scores<512><<<cN1 / 4, 256, 0, stream>>>(x1, wts2, wtd2, a_s2, a_d2, cN1, cN2);
  gat_hist<<<(E2 + 255) / 256, 256, 0, stream>>>(dst2, cnt2, E2);
  gat_scan_excl<<<1, 1024, 0, stream>>>(cnt2, off2, cN2);
  gat_scatter_edge<<<(E2 + 255) / 256, 256, 0, stream>>>(src2, dst2, a_s2, a_d2, off2, cur2, srcs2, exs2, E2);
  gat_denom<<<(cN2 + 3) / 4, 256, 0, stream>>>(exs2, off2, den2, cN2);
  for (int c = 0; c < cN2 / CH2; c++) {
    int d0 = c * CH2;
    gat_gather_in2<<<CH2, 256, 0, stream>>>(x1, exs2, den2, off2, srcs2, aggB, d0);
    gat_gemm<128, 2><<<dim3((CH2 + 63) / 64, 2, 1), 256, 0, stream>>>(
        aggB, 4096, W2te, 4096, (float*)d_out + (size_t)d0 * 256, 256,
        CH2, 4096, b2, 0, 0, 0, 0);
  }
}

// Round 6
// 854.932 us; speedup vs baseline: 1.7435x; 1.1121x over previous
//
#include <hip/hip_runtime.h>
#include <hip/hip_bf16.h>
#include <cstdint>

typedef __attribute__((ext_vector_type(8))) short short8;
typedef __attribute__((ext_vector_type(4))) float floatx4;
typedef __hip_bfloat16 bf16;
typedef unsigned short u16;

static constexpr int cN0 = 120000, cN1 = 24000, cN2 = 6000;
static constexpr int cD = 256, cHC1 = 512;
static constexpr int CH1 = 4800;   // layer-1 target chunk (5 chunks, %64==0)

// ---------- W1t[n*256+k] = bf16(W1[k*512+n]) ----------
__global__ __launch_bounds__(256)
void gat_w1t(const float* __restrict__ W1, u16* __restrict__ dst) {
  int t = blockIdx.x * 256 + threadIdx.x;  // t = n*256+k
  if (t >= 512 * 256) return;
  int n = t >> 8, k = t & 255;
  bf16 v = bf16(W1[(size_t)k * 512 + n]);
  dst[t] = *(u16*)&v;
}

// ---------- W2te[c*4096 + h*512 + k] = bf16(W2[k*2048 + h*256 + c]) ----------
__global__ __launch_bounds__(256)
void gat_make_w2te(const float* __restrict__ W2, u16* __restrict__ out) {
  __shared__ u16 tile[32][33];
  int kt = blockIdx.x * 32, ct = blockIdx.y * 32, h = blockIdx.z;
  int tx = threadIdx.x & 31, ty4 = (threadIdx.x >> 5) * 4;
#pragma unroll
  for (int i = 0; i < 4; i++) {
    int k = kt + ty4 + i, c = ct + tx;
    bf16 v = bf16(W2[(size_t)k * 2048 + h * 256 + c]);
    tile[ty4 + i][tx] = *(u16*)&v;
  }
  __syncthreads();
#pragma unroll
  for (int i = 0; i < 4; i++) {
    int c = ct + ty4 + i, k = kt + tx;
    out[(size_t)c * 4096 + h * 512 + k] = tile[tx][ty4 + i];
  }
}

// ---------- watt[h*K+k] = sum_c W[k*ldw + h*Ch + c] * att[h*Ch+c]  (f32) ----------
__global__ __launch_bounds__(256)
void gat_make_watt(const float* __restrict__ W, const float* __restrict__ atts,
                   const float* __restrict__ attd, float* __restrict__ ws,
                   float* __restrict__ wd, int K, int Ch, int ldw) {
  int lane = threadIdx.x & 63;
  int task = blockIdx.x * 4 + (threadIdx.x >> 6);  // task = h*K + k
  if (task >= 8 * K) return;
  int h = task / K, k = task - h * K;
  const float* Wr = W + (size_t)k * ldw + h * Ch;
  const float* as = atts + h * Ch;
  const float* ad = attd + h * Ch;
  float ss = 0.f, dd = 0.f;
  for (int c = lane; c < Ch; c += 64) {
    float wv = Wr[c];
    ss += wv * as[c];
    dd += wv * ad[c];
  }
#pragma unroll
  for (int o = 32; o; o >>= 1) { ss += __shfl_down(ss, o); dd += __shfl_down(dd, o); }
  if (lane == 0) { ws[task] = ss; wd[task] = dd; }
}

// ---------- scores via LDS staging: 16 rows/block, thread = (row, out16) ----------
// out<8 -> a_s[row,out] = x[row,:].wsrc[out,:]; out>=8 -> a_d[row,out-8] (row<MD)
template<int K>
__global__ __launch_bounds__(256)
void gat_scores_lds(const float* __restrict__ x, const float* __restrict__ wsrc,
                    const float* __restrict__ wdst, float* __restrict__ a_s,
                    float* __restrict__ a_d, int M, int MD) {
  constexpr int STR = K + 4;           // +4 floats: rows stay 16B-aligned, banks spread
  __shared__ float xs[16][STR];
  int row16 = blockIdx.x * 16;
  int tid = threadIdx.x;
#pragma unroll
  for (int base = 0; base < 16 * K; base += 1024) {
    int idx = base + tid * 4;
    int rr = idx / K, cc = idx - rr * K;
    int grow = row16 + rr; if (grow >= M) grow = M - 1;
    *(float4*)&xs[rr][cc] = *(const float4*)&x[(size_t)grow * K + cc];
  }
  __syncthreads();
  int rr = tid >> 4, out = tid & 15;
  int row = row16 + rr;
  const float* wp = (out < 8) ? (wsrc + out * K) : (wdst + (out - 8) * K);
  float acc = 0.f;
#pragma unroll 4
  for (int c = 0; c < K; c += 4) {
    float4 xv = *(const float4*)&xs[rr][c];
    float4 wv = *(const float4*)&wp[c];
    acc += xv.x * wv.x + xv.y * wv.y + xv.z * wv.z + xv.w * wv.w;
  }
  if (row < M) {
    if (out < 8) a_s[row * 8 + out] = acc;
    else if (row < MD) a_d[row * 8 + (out - 8)] = acc;
  }
}

// ---------- CSR build ----------
__global__ __launch_bounds__(256)
void gat_hist(const int* __restrict__ dstv, int* __restrict__ cnt, int E) {
  int t = blockIdx.x * 256 + threadIdx.x;
  if (t < E) atomicAdd(&cnt[dstv[t]], 1);
}

__global__ __launch_bounds__(1024)
void gat_scan_excl(const int* __restrict__ cnt, int* __restrict__ off, int n) {
  __shared__ int wsum[16];
  __shared__ int carry_s;
  int t = threadIdx.x, lane = t & 63, wid = t >> 6;
  if (t == 0) carry_s = 0;
  __syncthreads();
  for (int base = 0; base < n; base += 1024) {
    int idx = base + t;
    int v = (idx < n) ? cnt[idx] : 0;
    int x = v;
#pragma unroll
    for (int d = 1; d < 64; d <<= 1) { int y = __shfl_up(x, d); if (lane >= d) x += y; }
    if (lane == 63) wsum[wid] = x;
    __syncthreads();
    if (t < 16) {
      int s = wsum[t];
#pragma unroll
      for (int d = 1; d < 16; d <<= 1) { int y = __shfl_up(s, d); if (t >= d) s += y; }
      wsum[t] = s;
    }
    __syncthreads();
    int prefix = carry_s + (wid ? wsum[wid - 1] : 0) + x - v;
    if (idx < n) off[idx] = prefix;
    int tot = wsum[15];
    __syncthreads();
    if (t == 0) carry_s += tot;
    __syncthreads();
  }
  if (threadIdx.x == 0) off[n] = carry_s;
}

// ---------- fused scatter+edge: claim CSR slot, write src & exp(leaky(e)) in slot order ----------
__global__ __launch_bounds__(256)
void gat_scatter_edge(const int* __restrict__ src, const int* __restrict__ dstv,
                      const float* __restrict__ a_s, const float* __restrict__ a_d,
                      const int* __restrict__ off, int* __restrict__ cur,
                      int* __restrict__ srcs, float* __restrict__ exs, int E) {
  int t = blockIdx.x * 256 + threadIdx.x;
  if (t >= E) return;
  int s = src[t], d = dstv[t];
  int slot = off[d] + atomicAdd(&cur[d], 1);
  srcs[slot] = s;
  const float* as = a_s + (size_t)s * 8;
  const float* ad = a_d + (size_t)d * 8;
  float4 s0 = *(const float4*)as, s1 = *(const float4*)(as + 4);
  float4 d0 = *(const float4*)ad, d1 = *(const float4*)(ad + 4);
  float ev[8] = { s0.x + d0.x, s0.y + d0.y, s0.z + d0.z, s0.w + d0.w,
                  s1.x + d1.x, s1.y + d1.y, s1.z + d1.z, s1.w + d1.w };
  float exv[8];
#pragma unroll
  for (int h = 0; h < 8; h++) {
    float e = ev[h];
    e = e > 0.f ? e : 0.2f * e;
    exv[h] = expf(e);  // shift-invariant softmax; |e| <~ 8 so no overflow
  }
  float4* op = (float4*)(exs + (size_t)slot * 8);
  op[0] = make_float4(exv[0], exv[1], exv[2], exv[3]);
  op[1] = make_float4(exv[4], exv[5], exv[6], exv[7]);
}

// ---------- per-dst denominators from slot-ordered exs (no atomics) ----------
__global__ __launch_bounds__(256)
void gat_denom(const float* __restrict__ exs, const int* __restrict__ off,
               float* __restrict__ den, int N) {
  int lane = threadIdx.x & 63;
  int d = blockIdx.x * 4 + (threadIdx.x >> 6);
  if (d >= N) return;
  int beg = off[d], end = off[d + 1];
  float s = 0.f;
  for (size_t idx = (size_t)beg * 8 + lane; idx < (size_t)end * 8; idx += 64)
    s += exs[idx];
#pragma unroll
  for (int o = 32; o >= 8; o >>= 1) s += __shfl_down(s, o);
  if (lane < 8) den[(size_t)d * 8 + lane] = s;
}

// ---------- layer-1 input-space gather: agg[d,h,k] = sum alpha_h x[s,k] -> bf16 ----------
__global__ __launch_bounds__(256)
void gat_gather_in1(const float* __restrict__ x, const float* __restrict__ exs,
                    const float* __restrict__ den, const int* __restrict__ off,
                    const int* __restrict__ srcs, u16* __restrict__ agg, int d0) {
  int d = d0 + blockIdx.x, t = threadIdx.x;  // t = k (0..255)
  int beg = off[d], end = off[d + 1];
  float inv[8];
#pragma unroll
  for (int j = 0; j < 8; j++) inv[j] = 1.f / den[(size_t)d * 8 + j];
  float acc[8] = {};
  int s_n = 0;
  if (beg < end) s_n = srcs[beg];
  for (int i = beg; i < end; i++) {
    int s = s_n;
    if (i + 1 < end) s_n = srcs[i + 1];
    float4 e0 = *(const float4*)&exs[(size_t)i * 8];
    float4 e1 = *(const float4*)&exs[(size_t)i * 8 + 4];
    float xv = x[(size_t)s * cD + t];
    acc[0] += e0.x * inv[0] * xv; acc[1] += e0.y * inv[1] * xv;
    acc[2] += e0.z * inv[2] * xv; acc[3] += e0.w * inv[3] * xv;
    acc[4] += e1.x * inv[4] * xv; acc[5] += e1.y * inv[5] * xv;
    acc[6] += e1.z * inv[6] * xv; acc[7] += e1.w * inv[7] * xv;
  }
  u16* ap = agg + (size_t)blockIdx.x * 2048 + t;
#pragma unroll
  for (int j = 0; j < 8; j++) {
    bf16 v = bf16(acc[j]);
    ap[(size_t)j * 256] = *(u16*)&v;
  }
}

// ---------- layer-2 input-space gather: agg[d,h,k] (k<512) -> bf16 ----------
__global__ __launch_bounds__(256)
void gat_gather_in2(const float* __restrict__ x1, const float* __restrict__ exs,
                    const float* __restrict__ den, const int* __restrict__ off,
                    const int* __restrict__ srcs, u16* __restrict__ agg, int d0) {
  int d = d0 + blockIdx.x, t = threadIdx.x;  // k pair: t, t+256
  int beg = off[d], end = off[d + 1];
  float inv[8];
#pragma unroll
  for (int j = 0; j < 8; j++) inv[j] = 1.f / den[(size_t)d * 8 + j];
  float acc0[8] = {}, acc1[8] = {};
  int s_n = 0;
  if (beg < end) s_n = srcs[beg];
  for (int i = beg; i < end; i++) {
    int s = s_n;
    if (i + 1 < end) s_n = srcs[i + 1];
    float4 e0 = *(const float4*)&exs[(size_t)i * 8];
    float4 e1 = *(const float4*)&exs[(size_t)i * 8 + 4];
    float al[8] = { e0.x * inv[0], e0.y * inv[1], e0.z * inv[2], e0.w * inv[3],
                    e1.x * inv[4], e1.y * inv[5], e1.z * inv[6], e1.w * inv[7] };
    float xv0 = x1[(size_t)s * cHC1 + t];
    float xv1 = x1[(size_t)s * cHC1 + t + 256];
#pragma unroll
    for (int j = 0; j < 8; j++) { acc0[j] += al[j] * xv0; acc1[j] += al[j] * xv1; }
  }
  u16* ap = agg + (size_t)blockIdx.x * 4096;
#pragma unroll
  for (int j = 0; j < 8; j++) {
    bf16 v0 = bf16(acc0[j]), v1 = bf16(acc1[j]);
    ap[(size_t)j * 512 + t]       = *(u16*)&v0;
    ap[(size_t)j * 512 + t + 256] = *(u16*)&v1;
  }
}

// ---------- GEMM: C = A[M,K] @ Bt[N,K]^T (bf16 in, f32 out), M-guarded ----------
// XOR-swizzled LDS (chunk ^ row&7): conflict-free b128 reads/writes.
// EPI=0: raw partial store (split-K); EPI=1: elu(v+bias)
template<int BN, int EPI>
__global__ __launch_bounds__(256)
void gat_gemm(const u16* __restrict__ A, long lda, const u16* __restrict__ Bt, long ldb,
              float* __restrict__ C, long ldc, int M, int K,
              const float* __restrict__ bias, int zA, int zB, long zC, int zBias) {
  __shared__ __align__(16) u16 Al[64 * 64];
  __shared__ __align__(16) u16 Bl[BN * 64];
  const int tid = threadIdx.x;
  const int bm = blockIdx.x << 6;
  const int n0 = blockIdx.y * BN;
  const int z = blockIdx.z;
  const u16* Ab = A + (size_t)z * zA;
  const u16* Bb = Bt + (size_t)z * zB + (size_t)n0 * ldb;
  const int wid = tid >> 6, lane = tid & 63;
  const int wm = (wid & 1) << 5, wn = (wid >> 1) * (BN / 2);
  const int q = lane >> 4, r = lane & 15;
  constexpr int NJ = BN / 32;
  floatx4 acc[2][NJ] = {};
  const int arow = tid >> 3;      // 0..31
  const int chunk = tid & 7;      // 8-u16 chunk index
  const int acol = chunk << 3;
  for (int k0 = 0; k0 < K; k0 += 64) {
    __syncthreads();
#pragma unroll
    for (int rr = 0; rr < 2; rr++) {
      int row = arow + rr * 32;
      int gr = bm + row; if (gr >= M) gr = M - 1;
      *(uint4*)&Al[row * 64 + ((chunk ^ (row & 7)) << 3)] =
          *(const uint4*)&Ab[(size_t)gr * lda + k0 + acol];
    }
#pragma unroll
    for (int rr = 0; rr < BN / 32; rr++) {
      int row = arow + rr * 32;
      *(uint4*)&Bl[row * 64 + ((chunk ^ (row & 7)) << 3)] =
          *(const uint4*)&Bb[(size_t)row * ldb + k0 + acol];
    }
    __syncthreads();
#pragma unroll
    for (int kk = 0; kk < 64; kk += 32) {
      const int cs = (((kk >> 3) + q) ^ (r & 7)) << 3;
      short8 af[2], bfr[NJ];
#pragma unroll
      for (int i = 0; i < 2; i++)  af[i]  = *(const short8*)&Al[(wm + i * 16 + r) * 64 + cs];
#pragma unroll
      for (int j = 0; j < NJ; j++) bfr[j] = *(const short8*)&Bl[(wn + j * 16 + r) * 64 + cs];
#pragma unroll
      for (int i = 0; i < 2; i++)
#pragma unroll
        for (int j = 0; j < NJ; j++)
          acc[i][j] = __builtin_amdgcn_mfma_f32_16x16x32_bf16(af[i], bfr[j], acc[i][j], 0, 0, 0);
    }
  }
  // C/D layout: col = lane&15 (n), row = quad*4 + reg (m)   [verified m89/m91]
#pragma unroll
  for (int i = 0; i < 2; i++)
#pragma unroll
    for (int j = 0; j < NJ; j++) {
      int gn = n0 + wn + j * 16 + r;
      float bv = (EPI == 1) ? bias[zBias * z + gn] : 0.f;
#pragma unroll
      for (int t2 = 0; t2 < 4; t2++) {
        int gm = bm + wm + i * 16 + q * 4 + t2;
        if (gm < M) {
          float v = acc[i][j][t2];
          if (EPI == 1) { v += bv; v = v > 0.f ? v : expm1f(v); }
          C[(size_t)z * zC + (size_t)gm * ldc + gn] = v;
        }
      }
    }
}

// ---------- split-K reduce + mean-over-heads + bias ----------
__global__ __launch_bounds__(256)
void gat_reduce4(const float* __restrict__ p, const float* __restrict__ bias,
                 float* __restrict__ out, int MN) {
  int t = blockIdx.x * 256 + threadIdx.x;
  if (t >= MN) return;
  size_t mn = (size_t)MN;
  float v = p[t] + p[t + mn] + p[t + 2 * mn] + p[t + 3 * mn];
  out[t] = v * 0.125f + bias[t & 255];
}

extern "C" void kernel_launch(void* const* d_in, const int* in_sizes, int n_in,
                              void* d_out, int out_size, void* d_ws, size_t ws_size,
                              hipStream_t stream) {
  const float* x    = (const float*)d_in[0];
  const int* src1   = (const int*)d_in[1];
  const int* dst1   = (const int*)d_in[2];
  const int* src2   = (const int*)d_in[3];
  const int* dst2   = (const int*)d_in[4];
  const float* W1   = (const float*)d_in[5];
  const float* atts1 = (const float*)d_in[6];
  const float* attd1 = (const float*)d_in[7];
  const float* b1   = (const float*)d_in[8];
  const float* W2   = (const float*)d_in[9];
  const float* atts2 = (const float*)d_in[10];
  const float* attd2 = (const float*)d_in[11];
  const float* b2   = (const float*)d_in[12];
  const int E1 = in_sizes[1], E2 = in_sizes[3];

  uint8_t* p = (uint8_t*)d_ws;
  auto alloc = [&](size_t b) { uint8_t* r = p; p += (b + 255) & ~(size_t)255; return r; };
  auto al = [](size_t b) { return (b + 255) & ~(size_t)255; };
  // persistent (~52 MB)
  float* x1   = (float*)alloc((size_t)cN1 * cHC1 * 4);
  u16*   W1t  = (u16*)alloc((size_t)512 * 256 * 2);
  u16*   W2te = (u16*)alloc((size_t)256 * 4096 * 2);
  float* wts1 = (float*)alloc(8 * 256 * 4);
  float* wtd1 = (float*)alloc(8 * 256 * 4);
  float* wts2 = (float*)alloc(8 * 512 * 4);
  float* wtd2 = (float*)alloc(8 * 512 * 4);
  uint8_t* scratch = p;
  // phase A (~51 MB)
  u16*   aggA  = (u16*)alloc((size_t)CH1 * 2048 * 2);
  float* a_s1  = (float*)alloc((size_t)cN0 * 32);
  float* a_d1  = (float*)alloc((size_t)cN1 * 32);
  float* exs1  = (float*)alloc((size_t)E1 * 32);
  int*   srcs1 = (int*)alloc((size_t)E1 * 4);
  int*   off1  = (int*)alloc((size_t)(cN1 + 1) * 4);
  float* den1  = (float*)alloc((size_t)cN1 * 32);
  uint8_t* zA = p;
  int*   cnt1 = (int*)alloc((size_t)cN1 * 4);
  int*   cur1 = (int*)alloc((size_t)cN1 * 4);
  size_t zAbytes = (size_t)(p - zA);

  // phase B sizing: pick single-shot M2=6000 if workspace allows, else 2x3000
  size_t fixedB = al((size_t)cN1 * 32) + al((size_t)cN2 * 32) + al((size_t)E2 * 32) +
                  al((size_t)E2 * 4) + al((size_t)(cN2 + 1) * 4) + al((size_t)cN2 * 32) +
                  2 * al((size_t)cN2 * 4);
  size_t usedPersist = (size_t)(scratch - (uint8_t*)d_ws);
  int M2 = 6000;
  if (usedPersist + al((size_t)6000 * 4096 * 2) + al(4ull * 6000 * 256 * 4) + fixedB > ws_size)
    M2 = 3000;
  int nch2 = 6000 / M2;
  // phase B aliases phase A
  p = scratch;
  u16*   aggB  = (u16*)alloc((size_t)M2 * 4096 * 2);
  float* pbuf  = (float*)alloc(4ull * M2 * 256 * 4);
  float* a_s2  = (float*)alloc((size_t)cN1 * 32);
  float* a_d2  = (float*)alloc((size_t)cN2 * 32);
  float* exs2  = (float*)alloc((size_t)E2 * 32);
  int*   srcs2 = (int*)alloc((size_t)E2 * 4);
  int*   off2  = (int*)alloc((size_t)(cN2 + 1) * 4);
  float* den2  = (float*)alloc((size_t)cN2 * 32);
  uint8_t* zB = p;
  int*   cnt2 = (int*)alloc((size_t)cN2 * 4);
  int*   cur2 = (int*)alloc((size_t)cN2 * 4);
  size_t zBbytes = (size_t)(p - zB);

  // ---- prep ----
  gat_w1t<<<(512 * 256 + 255) / 256, 256, 0, stream>>>(W1, W1t);
  gat_make_w2te<<<dim3(16, 8, 8), 256, 0, stream>>>(W2, W2te);
  gat_make_watt<<<2 * 256, 256, 0, stream>>>(W1, atts1, attd1, wts1, wtd1, 256, 64, 512);
  gat_make_watt<<<2 * 512, 256, 0, stream>>>(W2, atts2, attd2, wts2, wtd2, 512, 256, 2048);

  // ---- layer 1 ----
  hipMemsetAsync(zA, 0, zAbytes, stream);
  gat_scores_lds<256><<<(cN0 + 15) / 16, 256, 0, stream>>>(x, wts1, wtd1, a_s1, a_d1, cN0, cN1);
  gat_hist<<<(E1 + 255) / 256, 256, 0, stream>>>(dst1, cnt1, E1);
  gat_scan_excl<<<1, 1024, 0, stream>>>(cnt1, off1, cN1);
  gat_scatter_edge<<<(E1 + 255) / 256, 256, 0, stream>>>(src1, dst1, a_s1, a_d1, off1, cur1, srcs1, exs1, E1);
  gat_denom<<<(cN1 + 3) / 4, 256, 0, stream>>>(exs1, off1, den1, cN1);
  for (int c = 0; c < cN1 / CH1; c++) {
    int d0 = c * CH1;
    gat_gather_in1<<<CH1, 256, 0, stream>>>(x, exs1, den1, off1, srcs1, aggA, d0);
    gat_gemm<64, 1><<<dim3(CH1 / 64, 1, 8), 256, 0, stream>>>(
        aggA, 2048, W1t, 256, x1 + (size_t)d0 * cHC1, cHC1,
        CH1, 256, b1, /*zA*/256, /*zB*/64 * 256, /*zC*/64, /*zBias*/64);
  }

  // ---- layer 2 ----
  hipMemsetAsync(zB, 0, zBbytes, stream);
  gat_scores_lds<512><<<(cN1 + 15) / 16, 256, 0, stream>>>(x1, wts2, wtd2, a_s2, a_d2, cN1, cN2);
  gat_hist<<<(E2 + 255) / 256, 256, 0, stream>>>(dst2, cnt2, E2);
  gat_scan_excl<<<1, 1024, 0, stream>>>(cnt2, off2, cN2);
  gat_scatter_edge<<<(E2 + 255) / 256, 256, 0, stream>>>(src2, dst2, a_s2, a_d2, off2, cur2, srcs2, exs2, E2);
  gat_denom<<<(cN2 + 3) / 4, 256, 0, stream>>>(exs2, off2, den2, cN2);
  for (int c = 0; c < nch2; c++) {
    int d0 = c * M2;
    gat_gather_in2<<<M2, 256, 0, stream>>>(x1, exs2, den2, off2, srcs2, aggB, d0);
    // split-K=4 over K=4096: z-offset 1024 elements into A rows and B rows
    gat_gemm<64, 0><<<dim3((M2 + 63) / 64, 4, 4), 256, 0, stream>>>(
        aggB, 4096, W2te, 4096, pbuf, 256,
        M2, 1024, nullptr, /*zA*/1024, /*zB*/1024, /*zC*/(long)M2 * 256, /*zBias*/0);
    gat_reduce4<<<(M2 * 256 + 255) / 256, 256, 0, stream>>>(
        pbuf, b2, (float*)d_out + (size_t)d0 * 256, M2 * 256);
  }
}

// Round 7
// 600.703 us; speedup vs baseline: 2.4814x; 1.4232x over previous
//
#include <hip/hip_runtime.h>
#include <hip/hip_bf16.h>
#include <cstdint>

typedef __attribute__((ext_vector_type(8))) short short8;
typedef __attribute__((ext_vector_type(4))) float floatx4;
typedef __hip_bfloat16 bf16;
typedef unsigned short u16;

static constexpr int cN0 = 120000, cN1 = 24000, cN2 = 6000;
static constexpr int cD = 256, cHC1 = 512;
static constexpr int CH1 = 4800;   // layer-1 target chunk (5 chunks, %64==0)

__device__ __forceinline__ float dot4(float4 a, float4 b) {
  return a.x * b.x + a.y * b.y + a.z * b.z + a.w * b.w;
}

// ---------- W1t[n*256+k] = bf16(W1[k*512+n]) ----------
__global__ __launch_bounds__(256)
void gat_w1t(const float* __restrict__ W1, u16* __restrict__ dst) {
  int t = blockIdx.x * 256 + threadIdx.x;  // t = n*256+k
  if (t >= 512 * 256) return;
  int n = t >> 8, k = t & 255;
  bf16 v = bf16(W1[(size_t)k * 512 + n]);
  dst[t] = *(u16*)&v;
}

// ---------- W2te[c*4096 + h*512 + k] = bf16(W2[k*2048 + h*256 + c]) ----------
__global__ __launch_bounds__(256)
void gat_make_w2te(const float* __restrict__ W2, u16* __restrict__ out) {
  __shared__ u16 tile[32][33];
  int kt = blockIdx.x * 32, ct = blockIdx.y * 32, h = blockIdx.z;
  int tx = threadIdx.x & 31, ty4 = (threadIdx.x >> 5) * 4;
#pragma unroll
  for (int i = 0; i < 4; i++) {
    int k = kt + ty4 + i, c = ct + tx;
    bf16 v = bf16(W2[(size_t)k * 2048 + h * 256 + c]);
    tile[ty4 + i][tx] = *(u16*)&v;
  }
  __syncthreads();
#pragma unroll
  for (int i = 0; i < 4; i++) {
    int c = ct + ty4 + i, k = kt + tx;
    out[(size_t)c * 4096 + h * 512 + k] = tile[tx][ty4 + i];
  }
}

// ---------- watt[h*K+k] = sum_c W[k*ldw + h*Ch + c] * att[h*Ch+c]  (f32) ----------
__global__ __launch_bounds__(256)
void gat_make_watt(const float* __restrict__ W, const float* __restrict__ atts,
                   const float* __restrict__ attd, float* __restrict__ ws,
                   float* __restrict__ wd, int K, int Ch, int ldw) {
  int lane = threadIdx.x & 63;
  int task = blockIdx.x * 4 + (threadIdx.x >> 6);  // task = h*K + k
  if (task >= 8 * K) return;
  int h = task / K, k = task - h * K;
  const float* Wr = W + (size_t)k * ldw + h * Ch;
  const float* as = atts + h * Ch;
  const float* ad = attd + h * Ch;
  float ss = 0.f, dd = 0.f;
  for (int c = lane; c < Ch; c += 64) {
    float wv = Wr[c];
    ss += wv * as[c];
    dd += wv * ad[c];
  }
#pragma unroll
  for (int o = 32; o; o >>= 1) { ss += __shfl_down(ss, o); dd += __shfl_down(dd, o); }
  if (lane == 0) { ws[task] = ss; wd[task] = dd; }
}

// ---- transposed butterfly reduce: 16 partials over 64 lanes in 15 shfl ----
// after stages, lane L (L<16) holds output o = bitrev4(L)
#define RSTAGE(HALF, MASK)                                              \
  {                                                                     \
    _Pragma("unroll") for (int j = 0; j < HALF; j++) {                  \
      float send = (lane & MASK) ? v[j] : v[j + HALF];                  \
      float rcv = __shfl_xor(send, MASK);                               \
      v[j] = ((lane & MASK) ? v[j + HALF] : v[j]) + rcv;                \
    }                                                                   \
  }

// ---------- scores K=256: one row per wave, w in 64 VGPRs ----------
__global__ __launch_bounds__(256)
void gat_scores_reg(const float* __restrict__ x, const float* __restrict__ wsrc,
                    const float* __restrict__ wdst, float* __restrict__ a_s,
                    float* __restrict__ a_d, int M, int MD) {
  int lane = threadIdx.x & 63;
  int wv = (blockIdx.x * 256 + threadIdx.x) >> 6;
  int nw = (gridDim.x * 256) >> 6;
  float4 w[16];
#pragma unroll
  for (int j = 0; j < 8; j++) {
    w[j]     = *(const float4*)&wsrc[j * 256 + lane * 4];
    w[j + 8] = *(const float4*)&wdst[j * 256 + lane * 4];
  }
  for (int row = wv; row < M; row += nw) {
    float4 xv = *(const float4*)&x[(size_t)row * 256 + lane * 4];
    float v[16];
#pragma unroll
    for (int j = 0; j < 16; j++) v[j] = dot4(xv, w[j]);
    RSTAGE(8, 1) RSTAGE(4, 2) RSTAGE(2, 4) RSTAGE(1, 8)
    v[0] += __shfl_xor(v[0], 16);
    v[0] += __shfl_xor(v[0], 32);
    if (lane < 16) {
      int o = ((lane & 1) << 3) | ((lane & 2) << 1) | ((lane & 4) >> 1) | ((lane & 8) >> 3);
      if (o < 8) a_s[row * 8 + o] = v[0];
      else if (row < MD) a_d[row * 8 + (o - 8)] = v[0];
    }
  }
}

// ---------- scores K=512: w staged in LDS (32 KB), one row per wave ----------
__global__ __launch_bounds__(256)
void gat_scores_w512(const float* __restrict__ x, const float* __restrict__ wsrc,
                     const float* __restrict__ wdst, float* __restrict__ a_s,
                     float* __restrict__ a_d, int M, int MD) {
  __shared__ float wl[16 * 512];
  int tid = threadIdx.x;
#pragma unroll
  for (int base = 0; base < 8192; base += 1024) {
    int idx = base + tid * 4;
    int j = idx >> 9, c = idx & 511;
    *(float4*)&wl[idx] = (j < 8) ? *(const float4*)&wsrc[j * 512 + c]
                                 : *(const float4*)&wdst[(j - 8) * 512 + c];
  }
  __syncthreads();
  int lane = tid & 63;
  int wv = (blockIdx.x * 256 + tid) >> 6;
  int nw = (gridDim.x * 256) >> 6;
  for (int row = wv; row < M; row += nw) {
    float4 xa = *(const float4*)&x[(size_t)row * 512 + lane * 4];
    float4 xb = *(const float4*)&x[(size_t)row * 512 + 256 + lane * 4];
    float v[16];
#pragma unroll
    for (int j = 0; j < 16; j++) {
      float4 wa = *(const float4*)&wl[j * 512 + lane * 4];
      float4 wb = *(const float4*)&wl[j * 512 + 256 + lane * 4];
      v[j] = dot4(xa, wa) + dot4(xb, wb);
    }
    RSTAGE(8, 1) RSTAGE(4, 2) RSTAGE(2, 4) RSTAGE(1, 8)
    v[0] += __shfl_xor(v[0], 16);
    v[0] += __shfl_xor(v[0], 32);
    if (lane < 16) {
      int o = ((lane & 1) << 3) | ((lane & 2) << 1) | ((lane & 4) >> 1) | ((lane & 8) >> 3);
      if (o < 8) a_s[row * 8 + o] = v[0];
      else if (row < MD) a_d[row * 8 + (o - 8)] = v[0];
    }
  }
}

// ---------- CSR build ----------
__global__ __launch_bounds__(256)
void gat_hist(const int* __restrict__ dstv, int* __restrict__ cnt, int E) {
  int t = blockIdx.x * 256 + threadIdx.x;
  if (t < E) atomicAdd(&cnt[dstv[t]], 1);
}

__global__ __launch_bounds__(1024)
void gat_scan_excl(const int* __restrict__ cnt, int* __restrict__ off, int n) {
  __shared__ int wsum[16];
  __shared__ int carry_s;
  int t = threadIdx.x, lane = t & 63, wid = t >> 6;
  if (t == 0) carry_s = 0;
  __syncthreads();
  for (int base = 0; base < n; base += 1024) {
    int idx = base + t;
    int v = (idx < n) ? cnt[idx] : 0;
    int x = v;
#pragma unroll
    for (int d = 1; d < 64; d <<= 1) { int y = __shfl_up(x, d); if (lane >= d) x += y; }
    if (lane == 63) wsum[wid] = x;
    __syncthreads();
    if (t < 16) {
      int s = wsum[t];
#pragma unroll
      for (int d = 1; d < 16; d <<= 1) { int y = __shfl_up(s, d); if (t >= d) s += y; }
      wsum[t] = s;
    }
    __syncthreads();
    int prefix = carry_s + (wid ? wsum[wid - 1] : 0) + x - v;
    if (idx < n) off[idx] = prefix;
    int tot = wsum[15];
    __syncthreads();
    if (t == 0) carry_s += tot;
    __syncthreads();
  }
  if (threadIdx.x == 0) off[n] = carry_s;
}

// ---------- fused scatter+edge ----------
__global__ __launch_bounds__(256)
void gat_scatter_edge(const int* __restrict__ src, const int* __restrict__ dstv,
                      const float* __restrict__ a_s, const float* __restrict__ a_d,
                      const int* __restrict__ off, int* __restrict__ cur,
                      int* __restrict__ srcs, float* __restrict__ exs, int E) {
  int t = blockIdx.x * 256 + threadIdx.x;
  if (t >= E) return;
  int s = src[t], d = dstv[t];
  int slot = off[d] + atomicAdd(&cur[d], 1);
  srcs[slot] = s;
  const float* as = a_s + (size_t)s * 8;
  const float* ad = a_d + (size_t)d * 8;
  float4 s0 = *(const float4*)as, s1 = *(const float4*)(as + 4);
  float4 d0 = *(const float4*)ad, d1 = *(const float4*)(ad + 4);
  float ev[8] = { s0.x + d0.x, s0.y + d0.y, s0.z + d0.z, s0.w + d0.w,
                  s1.x + d1.x, s1.y + d1.y, s1.z + d1.z, s1.w + d1.w };
  float exv[8];
#pragma unroll
  for (int h = 0; h < 8; h++) {
    float e = ev[h];
    e = e > 0.f ? e : 0.2f * e;
    exv[h] = expf(e);  // shift-invariant softmax; |e| <~ 8 so no overflow
  }
  float4* op = (float4*)(exs + (size_t)slot * 8);
  op[0] = make_float4(exv[0], exv[1], exv[2], exv[3]);
  op[1] = make_float4(exv[4], exv[5], exv[6], exv[7]);
}

// ---------- per-dst denominators (no atomics) ----------
__global__ __launch_bounds__(256)
void gat_denom(const float* __restrict__ exs, const int* __restrict__ off,
               float* __restrict__ den, int N) {
  int lane = threadIdx.x & 63;
  int d = blockIdx.x * 4 + (threadIdx.x >> 6);
  if (d >= N) return;
  int beg = off[d], end = off[d + 1];
  float s = 0.f;
  for (size_t idx = (size_t)beg * 8 + lane; idx < (size_t)end * 8; idx += 64)
    s += exs[idx];
#pragma unroll
  for (int o = 32; o >= 8; o >>= 1) s += __shfl_down(s, o);
  if (lane < 8) den[(size_t)d * 8 + lane] = s;
}

// ---------- layer-1 input-space gather ----------
__global__ __launch_bounds__(256)
void gat_gather_in1(const float* __restrict__ x, const float* __restrict__ exs,
                    const float* __restrict__ den, const int* __restrict__ off,
                    const int* __restrict__ srcs, u16* __restrict__ agg, int d0) {
  int d = d0 + blockIdx.x, t = threadIdx.x;  // t = k (0..255)
  int beg = off[d], end = off[d + 1];
  float inv[8];
#pragma unroll
  for (int j = 0; j < 8; j++) inv[j] = 1.f / den[(size_t)d * 8 + j];
  float acc[8] = {};
  int s_n = 0;
  if (beg < end) s_n = srcs[beg];
  for (int i = beg; i < end; i++) {
    int s = s_n;
    if (i + 1 < end) s_n = srcs[i + 1];
    float4 e0 = *(const float4*)&exs[(size_t)i * 8];
    float4 e1 = *(const float4*)&exs[(size_t)i * 8 + 4];
    float xv = x[(size_t)s * cD + t];
    acc[0] += e0.x * inv[0] * xv; acc[1] += e0.y * inv[1] * xv;
    acc[2] += e0.z * inv[2] * xv; acc[3] += e0.w * inv[3] * xv;
    acc[4] += e1.x * inv[4] * xv; acc[5] += e1.y * inv[5] * xv;
    acc[6] += e1.z * inv[6] * xv; acc[7] += e1.w * inv[7] * xv;
  }
  u16* ap = agg + (size_t)blockIdx.x * 2048 + t;
#pragma unroll
  for (int j = 0; j < 8; j++) {
    bf16 v = bf16(acc[j]);
    ap[(size_t)j * 256] = *(u16*)&v;
  }
}

// ---------- layer-2 input-space gather ----------
__global__ __launch_bounds__(256)
void gat_gather_in2(const float* __restrict__ x1, const float* __restrict__ exs,
                    const float* __restrict__ den, const int* __restrict__ off,
                    const int* __restrict__ srcs, u16* __restrict__ agg, int d0) {
  int d = d0 + blockIdx.x, t = threadIdx.x;  // k pair: t, t+256
  int beg = off[d], end = off[d + 1];
  float inv[8];
#pragma unroll
  for (int j = 0; j < 8; j++) inv[j] = 1.f / den[(size_t)d * 8 + j];
  float acc0[8] = {}, acc1[8] = {};
  int s_n = 0;
  if (beg < end) s_n = srcs[beg];
  for (int i = beg; i < end; i++) {
    int s = s_n;
    if (i + 1 < end) s_n = srcs[i + 1];
    float4 e0 = *(const float4*)&exs[(size_t)i * 8];
    float4 e1 = *(const float4*)&exs[(size_t)i * 8 + 4];
    float al[8] = { e0.x * inv[0], e0.y * inv[1], e0.z * inv[2], e0.w * inv[3],
                    e1.x * inv[4], e1.y * inv[5], e1.z * inv[6], e1.w * inv[7] };
    float xv0 = x1[(size_t)s * cHC1 + t];
    float xv1 = x1[(size_t)s * cHC1 + t + 256];
#pragma unroll
    for (int j = 0; j < 8; j++) { acc0[j] += al[j] * xv0; acc1[j] += al[j] * xv1; }
  }
  u16* ap = agg + (size_t)blockIdx.x * 4096;
#pragma unroll
  for (int j = 0; j < 8; j++) {
    bf16 v0 = bf16(acc0[j]), v1 = bf16(acc1[j]);
    ap[(size_t)j * 512 + t]       = *(u16*)&v0;
    ap[(size_t)j * 512 + t + 256] = *(u16*)&v1;
  }
}

// ---------- GEMM: C = A[M,K] @ Bt[N,K]^T (bf16 in, f32 out), M-guarded ----------
// XOR-swizzled LDS: conflict-free b128. EPI=0: raw partial; EPI=1: elu(v+bias)
template<int BN, int EPI>
__global__ __launch_bounds__(256)
void gat_gemm(const u16* __restrict__ A, long lda, const u16* __restrict__ Bt, long ldb,
              float* __restrict__ C, long ldc, int M, int K,
              const float* __restrict__ bias, int zA, int zB, long zC, int zBias) {
  __shared__ __align__(16) u16 Al[64 * 64];
  __shared__ __align__(16) u16 Bl[BN * 64];
  const int tid = threadIdx.x;
  const int bm = blockIdx.x << 6;
  const int n0 = blockIdx.y * BN;
  const int z = blockIdx.z;
  const u16* Ab = A + (size_t)z * zA;
  const u16* Bb = Bt + (size_t)z * zB + (size_t)n0 * ldb;
  const int wid = tid >> 6, lane = tid & 63;
  const int wm = (wid & 1) << 5, wn = (wid >> 1) * (BN / 2);
  const int q = lane >> 4, r = lane & 15;
  constexpr int NJ = BN / 32;
  floatx4 acc[2][NJ] = {};
  const int arow = tid >> 3;      // 0..31
  const int chunk = tid & 7;      // 8-u16 chunk index
  const int acol = chunk << 3;
  for (int k0 = 0; k0 < K; k0 += 64) {
    __syncthreads();
#pragma unroll
    for (int rr = 0; rr < 2; rr++) {
      int row = arow + rr * 32;
      int gr = bm + row; if (gr >= M) gr = M - 1;
      *(uint4*)&Al[row * 64 + ((chunk ^ (row & 7)) << 3)] =
          *(const uint4*)&Ab[(size_t)gr * lda + k0 + acol];
    }
#pragma unroll
    for (int rr = 0; rr < BN / 32; rr++) {
      int row = arow + rr * 32;
      *(uint4*)&Bl[row * 64 + ((chunk ^ (row & 7)) << 3)] =
          *(const uint4*)&Bb[(size_t)row * ldb + k0 + acol];
    }
    __syncthreads();
#pragma unroll
    for (int kk = 0; kk < 64; kk += 32) {
      const int cs = (((kk >> 3) + q) ^ (r & 7)) << 3;
      short8 af[2], bfr[NJ];
#pragma unroll
      for (int i = 0; i < 2; i++)  af[i]  = *(const short8*)&Al[(wm + i * 16 + r) * 64 + cs];
#pragma unroll
      for (int j = 0; j < NJ; j++) bfr[j] = *(const short8*)&Bl[(wn + j * 16 + r) * 64 + cs];
#pragma unroll
      for (int i = 0; i < 2; i++)
#pragma unroll
        for (int j = 0; j < NJ; j++)
          acc[i][j] = __builtin_amdgcn_mfma_f32_16x16x32_bf16(af[i], bfr[j], acc[i][j], 0, 0, 0);
    }
  }
  // C/D layout: col = lane&15 (n), row = quad*4 + reg (m)
#pragma unroll
  for (int i = 0; i < 2; i++)
#pragma unroll
    for (int j = 0; j < NJ; j++) {
      int gn = n0 + wn + j * 16 + r;
      float bv = (EPI == 1) ? bias[zBias * z + gn] : 0.f;
#pragma unroll
      for (int t2 = 0; t2 < 4; t2++) {
        int gm = bm + wm + i * 16 + q * 4 + t2;
        if (gm < M) {
          float v = acc[i][j][t2];
          if (EPI == 1) { v += bv; v = v > 0.f ? v : expm1f(v); }
          C[(size_t)z * zC + (size_t)gm * ldc + gn] = v;
        }
      }
    }
}

// ---------- split-K reduce + mean-over-heads + bias ----------
__global__ __launch_bounds__(256)
void gat_reduce4(const float* __restrict__ p, const float* __restrict__ bias,
                 float* __restrict__ out, int MN) {
  int t = blockIdx.x * 256 + threadIdx.x;
  if (t >= MN) return;
  size_t mn = (size_t)MN;
  float v = p[t] + p[t + mn] + p[t + 2 * mn] + p[t + 3 * mn];
  out[t] = v * 0.125f + bias[t & 255];
}

extern "C" void kernel_launch(void* const* d_in, const int* in_sizes, int n_in,
                              void* d_out, int out_size, void* d_ws, size_t ws_size,
                              hipStream_t stream) {
  const float* x    = (const float*)d_in[0];
  const int* src1   = (const int*)d_in[1];
  const int* dst1   = (const int*)d_in[2];
  const int* src2   = (const int*)d_in[3];
  const int* dst2   = (const int*)d_in[4];
  const float* W1   = (const float*)d_in[5];
  const float* atts1 = (const float*)d_in[6];
  const float* attd1 = (const float*)d_in[7];
  const float* b1   = (const float*)d_in[8];
  const float* W2   = (const float*)d_in[9];
  const float* atts2 = (const float*)d_in[10];
  const float* attd2 = (const float*)d_in[11];
  const float* b2   = (const float*)d_in[12];
  const int E1 = in_sizes[1], E2 = in_sizes[3];

  uint8_t* p = (uint8_t*)d_ws;
  auto alloc = [&](size_t b) { uint8_t* r = p; p += (b + 255) & ~(size_t)255; return r; };
  auto al = [](size_t b) { return (b + 255) & ~(size_t)255; };
  // persistent (~52 MB)
  float* x1   = (float*)alloc((size_t)cN1 * cHC1 * 4);
  u16*   W1t  = (u16*)alloc((size_t)512 * 256 * 2);
  u16*   W2te = (u16*)alloc((size_t)256 * 4096 * 2);
  float* wts1 = (float*)alloc(8 * 256 * 4);
  float* wtd1 = (float*)alloc(8 * 256 * 4);
  float* wts2 = (float*)alloc(8 * 512 * 4);
  float* wtd2 = (float*)alloc(8 * 512 * 4);
  uint8_t* scratch = p;
  // phase A (~51 MB)
  u16*   aggA  = (u16*)alloc((size_t)CH1 * 2048 * 2);
  float* a_s1  = (float*)alloc((size_t)cN0 * 32);
  float* a_d1  = (float*)alloc((size_t)cN1 * 32);
  float* exs1  = (float*)alloc((size_t)E1 * 32);
  int*   srcs1 = (int*)alloc((size_t)E1 * 4);
  int*   off1  = (int*)alloc((size_t)(cN1 + 1) * 4);
  float* den1  = (float*)alloc((size_t)cN1 * 32);
  uint8_t* zA = p;
  int*   cnt1 = (int*)alloc((size_t)cN1 * 4);
  int*   cur1 = (int*)alloc((size_t)cN1 * 4);
  size_t zAbytes = (size_t)(p - zA);

  // phase B sizing: pick single-shot M2=6000 if workspace allows, else 2x3000
  size_t fixedB = al((size_t)cN1 * 32) + al((size_t)cN2 * 32) + al((size_t)E2 * 32) +
                  al((size_t)E2 * 4) + al((size_t)(cN2 + 1) * 4) + al((size_t)cN2 * 32) +
                  2 * al((size_t)cN2 * 4);
  size_t usedPersist = (size_t)(scratch - (uint8_t*)d_ws);
  int M2 = 6000;
  if (usedPersist + al((size_t)6000 * 4096 * 2) + al(4ull * 6000 * 256 * 4) + fixedB > ws_size)
    M2 = 3000;
  int nch2 = 6000 / M2;
  // phase B aliases phase A
  p = scratch;
  u16*   aggB  = (u16*)alloc((size_t)M2 * 4096 * 2);
  float* pbuf  = (float*)alloc(4ull * M2 * 256 * 4);
  float* a_s2  = (float*)alloc((size_t)cN1 * 32);
  float* a_d2  = (float*)alloc((size_t)cN2 * 32);
  float* exs2  = (float*)alloc((size_t)E2 * 32);
  int*   srcs2 = (int*)alloc((size_t)E2 * 4);
  int*   off2  = (int*)alloc((size_t)(cN2 + 1) * 4);
  float* den2  = (float*)alloc((size_t)cN2 * 32);
  uint8_t* zB = p;
  int*   cnt2 = (int*)alloc((size_t)cN2 * 4);
  int*   cur2 = (int*)alloc((size_t)cN2 * 4);
  size_t zBbytes = (size_t)(p - zB);

  // ---- prep ----
  gat_w1t<<<(512 * 256 + 255) / 256, 256, 0, stream>>>(W1, W1t);
  gat_make_w2te<<<dim3(16, 8, 8), 256, 0, stream>>>(W2, W2te);
  gat_make_watt<<<2 * 256, 256, 0, stream>>>(W1, atts1, attd1, wts1, wtd1, 256, 64, 512);
  gat_make_watt<<<2 * 512, 256, 0, stream>>>(W2, atts2, attd2, wts2, wtd2, 512, 256, 2048);

  // ---- layer 1 ----
  hipMemsetAsync(zA, 0, zAbytes, stream);
  gat_scores_reg<<<1024, 256, 0, stream>>>(x, wts1, wtd1, a_s1, a_d1, cN0, cN1);
  gat_hist<<<(E1 + 255) / 256, 256, 0, stream>>>(dst1, cnt1, E1);
  gat_scan_excl<<<1, 1024, 0, stream>>>(cnt1, off1, cN1);
  gat_scatter_edge<<<(E1 + 255) / 256, 256, 0, stream>>>(src1, dst1, a_s1, a_d1, off1, cur1, srcs1, exs1, E1);
  gat_denom<<<(cN1 + 3) / 4, 256, 0, stream>>>(exs1, off1, den1, cN1);
  for (int c = 0; c < cN1 / CH1; c++) {
    int d0 = c * CH1;
    gat_gather_in1<<<CH1, 256, 0, stream>>>(x, exs1, den1, off1, srcs1, aggA, d0);
    gat_gemm<64, 1><<<dim3(CH1 / 64, 1, 8), 256, 0, stream>>>(
        aggA, 2048, W1t, 256, x1 + (size_t)d0 * cHC1, cHC1,
        CH1, 256, b1, /*zA*/256, /*zB*/64 * 256, /*zC*/64, /*zBias*/64);
  }

  // ---- layer 2 ----
  hipMemsetAsync(zB, 0, zBbytes, stream);
  gat_scores_w512<<<512, 256, 0, stream>>>(x1, wts2, wtd2, a_s2, a_d2, cN1, cN2);
  gat_hist<<<(E2 + 255) / 256, 256, 0, stream>>>(dst2, cnt2, E2);
  gat_scan_excl<<<1, 1024, 0, stream>>>(cnt2, off2, cN2);
  gat_scatter_edge<<<(E2 + 255) / 256, 256, 0, stream>>>(src2, dst2, a_s2, a_d2, off2, cur2, srcs2, exs2, E2);
  gat_denom<<<(cN2 + 3) / 4, 256, 0, stream>>>(exs2, off2, den2, cN2);
  for (int c = 0; c < nch2; c++) {
    int d0 = c * M2;
    gat_gather_in2<<<M2, 256, 0, stream>>>(x1, exs2, den2, off2, srcs2, aggB, d0);
    gat_gemm<64, 0><<<dim3((M2 + 63) / 64, 4, 4), 256, 0, stream>>>(
        aggB, 4096, W2te, 4096, pbuf, 256,
        M2, 1024, nullptr, /*zA*/1024, /*zB*/1024, /*zC*/(long)M2 * 256, /*zBias*/0);
    gat_reduce4<<<(M2 * 256 + 255) / 256, 256, 0, stream>>>(
        pbuf, b2, (float*)d_out + (size_t)d0 * 256, M2 * 256);
  }
}